// Round 5
// baseline (229.286 us; speedup 1.0000x reference)
//
#include <hip/hip_runtime.h>
#include <math.h>

// ---------------------------------------------------------------------------
// Restormer block, B=1 DIM=3 NC=512 HEADS=2 -> CT=768, NT=32, HID=6. f32 I/O.
//
// R18: (a) k_prep + k_corr + k_scat merged into one kernel k_pre: tap trios
// computed per 16-row band (3 ci per block), staged in LDS, assembled into
// GB2 rows and written as coalesced 64B stores (no T3 global round-trip);
// prep tasks run in 3 extra blocks. 6 -> 4 launches.
// (b) k_mlp: double-buffered y1 tile -> ONE barrier per chunk (16 vs 32),
// stage-2(t) and stage-1(t+1) issued back-to-back after each barrier
// (independent MFMA chains overlap), GB2/w2 frags prefetched a chunk ahead.
// k_attn / k_ffn unchanged from R17.
// ---------------------------------------------------------------------------

__device__ __forceinline__ float sigm(float s) {
    return __builtin_amdgcn_rcpf(1.f + __expf(-s));
}

using bf16x8 = __attribute__((ext_vector_type(8))) short;     // 8 bf16 (4 VGPRs)
using f16x8  = __attribute__((ext_vector_type(8))) _Float16;  // 8 f16  (4 VGPRs)
using f32x16 = __attribute__((ext_vector_type(16))) float;

__device__ __forceinline__ unsigned short f2bf(float f) {
    union { __bf16 h; unsigned short s; } u;
    u.h = (__bf16)f;                    // HW cvt, RNE
    return u.s;
}
__device__ __forceinline__ unsigned short f2h(float f) {
    union { _Float16 h; unsigned short s; } u;
    u.h = (_Float16)f;                  // HW cvt, RNE
    return u.s;
}

// ---- f32 workspace layout (element offsets) -------------------------------
// GB2: tap tensor, f16. u16 index = ((v*32 + n)*512 + h)*32 + k,
//      k = ci*9 + dy*3 + dx (k=27..31 zero; h-edge dy slots zero).
static constexpr int OFF_GB  = 0;          // 1,572,864 u16 = 786,432 f32
static constexpr int OFF_S1  = 786432;     // [3v][32] column sums of w1 (96)
static constexpr int OFF_CWB = 786528;     // cw f16 pack [768c][32k] = 12288 f32
static constexpr int OFF_SC  = 798816;     // w2 bf16 B-frag pack [3v][32hc][64lane][uint4] = 24576 f32
static constexpr int OFF_QKV = 823392;     // ushort: Qb[4][768][256] | Kb | Vt[4][256][768] = 1179648 f32
static constexpr int OFF_ATT = 2003040;    // [4head][768][256] f32 == (3,512,512) flat
// total 2,789,472 floats = 11.2 MB

struct MlpPtrs {
    const float* b1[3];
    const float* w2[3];
    const float* b2[3];
};

// ---------------------------------------------------------------------------
// k_pre: grid (33, 3) x 512 thr.
// Blocks x<32, v=blockIdx.y: tap trios for output rows h0..h0+15 (sources
// h0-1..h0+16, 3 ci) via the rolling-register dot loop, staged in LDS tp,
// then GB2 rows assembled and written as 4x uint4 per (n,h).
// Blocks x==32: prep tasks (S1 sums, w2 bf16 frags, cw f16 pack).
// ---------------------------------------------------------------------------
__global__ __launch_bounds__(512) void k_pre(const float* __restrict__ x,
                                             const float* __restrict__ qw1,
                                             const float* __restrict__ kw1,
                                             const float* __restrict__ vw1,
                                             const float* __restrict__ cwp,
                                             MlpPtrs mp,
                                             float* __restrict__ ws) {
    const int v = blockIdx.y;
    const int tid = threadIdx.x;

    if (blockIdx.x == 32) {                 // ---- prep tasks ----
        const int gt = v * 512 + tid;       // 0..1535
        {                                   // S1: 24 waves x 4 items
            const int gw = gt >> 6, lane = gt & 63;
#pragma unroll
            for (int jj = 0; jj < 4; jj++) {
                const int j = gw * 4 + jj;  // 0..95
                const int vv = j >> 5, n = j & 31;
                const float* w1p = (vv == 0) ? qw1 : ((vv == 1) ? kw1 : vw1);
                float s = 0.f;
#pragma unroll
                for (int k = 0; k < 8; k++) s += w1p[(lane + 64 * k) * 32 + n];
#pragma unroll
                for (int off = 32; off > 0; off >>= 1) s += __shfl_xor(s, off);
                if (lane == 0) ws[OFF_S1 + j] = s;
            }
        }
        {                                   // w2 -> bf16 B-fragments (4 each)
            uint4* dst = (uint4*)(ws + OFF_SC);
#pragma unroll
            for (int q = 0; q < 4; q++) {
                const int jj = gt * 4 + q;  // 0..6143
                const int vv = jj >> 11, r = jj & 2047;
                const int hc = r >> 6, lane2 = r & 63;
                const int o = lane2 & 31, hf = lane2 >> 5;
                const int H = hc * 16 + hf * 8;
                const float* w2p = mp.w2[vv];
                unsigned int d[4];
#pragma unroll
                for (int t = 0; t < 4; t++) {
                    unsigned int lo = f2bf(w2p[(H + 2 * t) * 32 + o]);
                    unsigned int hi = f2bf(w2p[(H + 2 * t + 1) * 32 + o]);
                    d[t] = (hi << 16) | lo;
                }
                dst[jj] = make_uint4(d[0], d[1], d[2], d[3]);
            }
        }
        if (gt < 768) {                     // cw -> f16 A-rows [c][32k]
            unsigned short* cwB = (unsigned short*)(ws + OFF_CWB);
#pragma unroll
            for (int k = 0; k < 32; k++)
                cwB[gt * 32 + k] = (k < 27) ? f2h(cwp[gt * 27 + k]) : (unsigned short)0;
        }
        return;
    }

    // ---- corr blocks ----
    const int h0 = blockIdx.x * 16;
    __shared__ __align__(16) float ws1t[32 * 516];          // 66 KB
    __shared__ __align__(16) uint2 tp[3][18][33];           // 14.3 KB, padded

    const float* w1f = (v == 0) ? qw1 : ((v == 1) ? kw1 : vw1);
    for (int i = tid; i < 4096; i += 512) {                 // transpose-stage w1
        int n_ = i & 31, u = (i >> 5) * 4;
        float a = w1f[(u + 0) * 32 + n_];
        float b = w1f[(u + 1) * 32 + n_];
        float c = w1f[(u + 2) * 32 + n_];
        float d = w1f[(u + 3) * 32 + n_];
        *(float4*)&ws1t[n_ * 516 + u] = make_float4(a, b, c, d);
    }
    if (tid < 32) *(float4*)&ws1t[tid * 516 + 512] = make_float4(0.f, 0.f, 0.f, 0.f);
    __syncthreads();

    const int hp = tid >> 5, n = tid & 31;
    // tasks tau = hp + 16*cc < 54: ci = tau/18, s = tau%18, h_src = h0+s-1
#pragma unroll
    for (int cc = 0; cc < 4; cc++) {
        const int tau = hp + 16 * cc;
        if (tau < 54) {
            const int ci = tau / 18, s = tau % 18;
            const int hs = h0 + s - 1;
            unsigned int lo = 0u, hi = 0u;
            if ((unsigned)hs < 512u) {
                const float* xrow = x + ci * 262144 + hs * 512;
                float a0 = 0.f, a1 = 0.f, a2 = 0.f, pq = 0.f;
                float4 cq = *(float4*)&ws1t[n * 516];
#pragma unroll 4
                for (int k = 0; k < 128; k++) {
                    float4 nq = *(float4*)&ws1t[n * 516 + 4 * k + 4];
                    float4 x4 = *(const float4*)&xrow[4 * k];
                    a1 = fmaf(x4.x, cq.x, a1); a1 = fmaf(x4.y, cq.y, a1);
                    a1 = fmaf(x4.z, cq.z, a1); a1 = fmaf(x4.w, cq.w, a1);
                    a0 = fmaf(x4.x, cq.y, a0); a0 = fmaf(x4.y, cq.z, a0);
                    a0 = fmaf(x4.z, cq.w, a0); a0 = fmaf(x4.w, nq.x, a0);
                    a2 = fmaf(x4.x, pq,   a2); a2 = fmaf(x4.y, cq.x, a2);
                    a2 = fmaf(x4.z, cq.y, a2); a2 = fmaf(x4.w, cq.z, a2);
                    pq = cq.w; cq = nq;
                }
                lo = ((unsigned int)f2h(a1) << 16) | f2h(a0);
                hi = (unsigned int)f2h(a2);
            }
            tp[ci][s][n] = make_uint2(lo, hi);
        }
    }
    __syncthreads();

    // scat: thread owns one GB2 row (nn, h = h0 + h_l)
    const int h_l = tid & 15, nn = tid >> 4;
    union { unsigned short ks[32]; uint4 q[4]; } o;
#pragma unroll
    for (int t = 0; t < 4; t++) o.q[t] = make_uint4(0u, 0u, 0u, 0u);
#pragma unroll
    for (int ci = 0; ci < 3; ci++)
#pragma unroll
        for (int dy = 0; dy < 3; dy++) {
            uint2 t2 = tp[ci][h_l + dy][nn];
            const int k = ci * 9 + dy * 3;
            o.ks[k]     = (unsigned short)(t2.x & 0xffffu);
            o.ks[k + 1] = (unsigned short)(t2.x >> 16);
            o.ks[k + 2] = (unsigned short)(t2.y & 0xffffu);
        }
    uint4* gb = (uint4*)ws;                                 // OFF_GB = 0
    const size_t base = ((size_t)(v * 32 + nn) * 512 + (h0 + h_l)) * 4;
#pragma unroll
    for (int t = 0; t < 4; t++) gb[base + t] = o.q[t];
}

// ---------------------------------------------------------------------------
// k_mlp: fused MFMA stage-1 + stage-2, double-buffered + pipelined.
// Block = 32 c x 4 n x 512 h, 256 thr = 4 waves (wave w: n_l = w in stage-1,
// M-tile w in stage-2). One barrier per 32-h chunk: after BAR, stage-2(t)
// (ds_read + 2 bf16 MFMA) and stage-1(t+1) (2 f16 MFMA + sigmoid + LDS
// write to the other buffer) issue together. GB2/w2 frags prefetched +1.
// grid (24 ctile, 8 nquad, 3 v) = 576 blocks.
// ---------------------------------------------------------------------------
__global__ __launch_bounds__(256) void k_mlp(const float* __restrict__ cbp,
                                             MlpPtrs mp, float* __restrict__ ws) {
    const int v = blockIdx.z;
    const int c0 = blockIdx.x * 32;
    const int n0 = blockIdx.y * 4;
    const int tid = threadIdx.x;
    const int w = tid >> 6, lane = tid & 63;
    const int m = lane & 31, half = lane >> 5;

    __shared__ __align__(16) unsigned short y1t[2][4096];   // 2 x 8 KB, swizzled

    const unsigned short* cwB = (const unsigned short*)(ws + OFF_CWB);
    const f16x8 afA0 = *(const f16x8*)(cwB + (c0 + m) * 32 + half * 8);
    const f16x8 afA1 = *(const f16x8*)(cwB + (c0 + m) * 32 + 16 + half * 8);

    const uint4* w2pk = (const uint4*)(ws + OFF_SC) + (size_t)v * 2048 + lane;

    int rowv[16];
#pragma unroll
    for (int r = 0; r < 16; r++) rowv[r] = (r & 3) + 8 * (r >> 2) + 4 * half;

    const float b1n = mp.b1[v][n0 + w];
    const float s1n = ws[OFF_S1 + v * 32 + n0 + w];
    float bases[16];
#pragma unroll
    for (int r = 0; r < 16; r++)
        bases[r] = b1n + cbp[c0 + rowv[r]] * s1n;

    const unsigned short* gbv = (const unsigned short*)ws
        + ((size_t)(v * 32 + n0 + w) * 512) * 32;

    f32x16 acc;
#pragma unroll
    for (int r = 0; r < 16; r++) acc[r] = 0.f;

    // stage-2 read addresses (fixed per thread)
    const int row2 = w * 32 + m;
    const int swz2 = (row2 & 7) << 4;
    const int byte0 = (row2 * 64 + half * 16) ^ swz2;
    const int byte1 = (row2 * 64 + 32 + half * 16) ^ swz2;

    // ---- prologue: chunk 0 stage-1 into buf0 ----
    {
        f16x8 cb0 = *(const f16x8*)(gbv + (size_t)m * 32 + half * 8);
        f16x8 cb1 = *(const f16x8*)(gbv + (size_t)m * 32 + 16 + half * 8);
        f32x16 s1a;
#pragma unroll
        for (int r = 0; r < 16; r++) s1a[r] = 0.f;
        s1a = __builtin_amdgcn_mfma_f32_32x32x16_f16(afA0, cb0, s1a, 0, 0, 0);
        s1a = __builtin_amdgcn_mfma_f32_32x32x16_f16(afA1, cb1, s1a, 0, 0, 0);
#pragma unroll
        for (int r = 0; r < 16; r++) {
            float y = sigm(s1a[r] + bases[r]);
            int row = rowv[r] * 4 + w;
            int byte = (row * 64 + m * 2) ^ ((row & 7) << 4);
            *(unsigned short*)((char*)y1t[0] + byte) = f2bf(y);
        }
    }
    // prefetch chunk 1 GB2 frags + chunk 0/1 w2 frags
    f16x8 nb0 = *(const f16x8*)(gbv + (size_t)(32 + m) * 32 + half * 8);
    f16x8 nb1 = *(const f16x8*)(gbv + (size_t)(32 + m) * 32 + 16 + half * 8);
    uint4 cw0 = w2pk[0],   cw1 = w2pk[64];
    uint4 nw0 = w2pk[128], nw1 = w2pk[192];

    for (int t = 0; t < 16; t++) {
        __syncthreads();
        // stage-2(t) from buf[t&1]
        {
            bf16x8 a0 = *(const bf16x8*)((char*)y1t[t & 1] + byte0);
            bf16x8 a1 = *(const bf16x8*)((char*)y1t[t & 1] + byte1);
            union { uint4 u; bf16x8 b; } u0, u1;
            u0.u = cw0; u1.u = cw1;
            acc = __builtin_amdgcn_mfma_f32_32x32x16_bf16(a0, u0.b, acc, 0, 0, 0);
            acc = __builtin_amdgcn_mfma_f32_32x32x16_bf16(a1, u1.b, acc, 0, 0, 0);
        }
        // stage-1(t+1) into buf[(t+1)&1]
        if (t < 15) {
            f32x16 s1a;
#pragma unroll
            for (int r = 0; r < 16; r++) s1a[r] = 0.f;
            s1a = __builtin_amdgcn_mfma_f32_32x32x16_f16(afA0, nb0, s1a, 0, 0, 0);
            s1a = __builtin_amdgcn_mfma_f32_32x32x16_f16(afA1, nb1, s1a, 0, 0, 0);
            f16x8 pb0, pb1; uint4 pw0, pw1;
            if (t < 14) {                       // prefetch chunk t+2
                const size_t nbo = (size_t)((t + 2) * 32 + m) * 32;
                pb0 = *(const f16x8*)(gbv + nbo + half * 8);
                pb1 = *(const f16x8*)(gbv + nbo + 16 + half * 8);
                pw0 = w2pk[(t + 2) * 128];
                pw1 = w2pk[(t + 2) * 128 + 64];
            }
#pragma unroll
            for (int r = 0; r < 16; r++) {
                float y = sigm(s1a[r] + bases[r]);
                int row = rowv[r] * 4 + w;
                int byte = (row * 64 + m * 2) ^ ((row & 7) << 4);
                *(unsigned short*)((char*)y1t[(t + 1) & 1] + byte) = f2bf(y);
            }
            cw0 = nw0; cw1 = nw1;
            if (t < 14) { nb0 = pb0; nb1 = pb1; nw0 = pw0; nw1 = pw1; }
        }
    }

    // epilogue
    const float b2v = mp.b2[v][m];                   // o = m
    unsigned short* uq = (unsigned short*)(ws + OFF_QKV);
#pragma unroll
    for (int r = 0; r < 16; r++) {
        int rowg = w * 32 + rowv[r];
        int c  = c0 + (rowg >> 2);
        int ny = n0 + (rowg & 3);
        float mm = sigm(acc[r] + b2v);
        int head = ((m & 1) << 1) | (ny & 1);
        int sidx = ((m >> 1) << 4) | (ny >> 1);
        if (v < 2)  uq[v * 786432 + head * 196608 + c * 256 + sidx] = f2bf(mm);
        else        uq[2 * 786432 + head * 196608 + sidx * 768 + c] = f2bf(mm);
    }
}

// ---------------------------------------------------------------------------
// k_attn: fused QK^T * temp -> softmax -> @V for one (head, 32-row band).
// Block 512 = 8 waves. grid (24 iband, 4 head).
// ---------------------------------------------------------------------------
__global__ __launch_bounds__(512) void k_attn(const float* __restrict__ tempr,
                                              float* __restrict__ ws) {
    const unsigned short* uq = (const unsigned short*)(ws + OFF_QKV);
    const int head = blockIdx.y;
    const int i0 = blockIdx.x * 32;
    const int w = threadIdx.x >> 6, lane = threadIdx.x & 63;
    const int m = lane & 31, half = lane >> 5;

    __shared__ __align__(16) unsigned short ap[32][776];   // attn bf16, padded
    __shared__ float mxw[8][32];
    __shared__ float smw[8][32];
    __shared__ float gmx[32];
    __shared__ float gsm[32];

    const float temp = tempr[head];
    const unsigned short* Qp = uq + head * 196608 + (i0 + m) * 256 + half * 8;

    // ---- phase 1: QK^T for 3 j-tiles --------------------------------------
    f32x16 acc[3];
#pragma unroll
    for (int t = 0; t < 3; t++)
#pragma unroll
        for (int r = 0; r < 16; r++) acc[t][r] = 0.f;
#pragma unroll
    for (int t = 0; t < 3; t++) {
        const int j0 = (w * 3 + t) * 32;
        const unsigned short* Kp = uq + 786432 + head * 196608 + (j0 + m) * 256 + half * 8;
#pragma unroll
        for (int kk = 0; kk < 16; kk++) {
            bf16x8 af = *(const bf16x8*)(Qp + kk * 16);
            bf16x8 bf = *(const bf16x8*)(Kp + kk * 16);
            acc[t] = __builtin_amdgcn_mfma_f32_32x32x16_bf16(af, bf, acc[t], 0, 0, 0);
        }
    }
#pragma unroll
    for (int t = 0; t < 3; t++)
#pragma unroll
        for (int r = 0; r < 16; r++) acc[t][r] *= temp;

    // ---- phase 2: block softmax -------------------------------------------
    int rowv[16];
#pragma unroll
    for (int r = 0; r < 16; r++) rowv[r] = (r & 3) + 8 * (r >> 2) + 4 * half;

    float rmx[16];
#pragma unroll
    for (int r = 0; r < 16; r++)
        rmx[r] = fmaxf(fmaxf(acc[0][r], acc[1][r]), acc[2][r]);
#pragma unroll
    for (int off = 16; off > 0; off >>= 1)
#pragma unroll
        for (int r = 0; r < 16; r++) rmx[r] = fmaxf(rmx[r], __shfl_xor(rmx[r], off));
    if (m == 0) {
#pragma unroll
        for (int r = 0; r < 16; r++) mxw[w][rowv[r]] = rmx[r];
    }
    __syncthreads();
    if (threadIdx.x < 32) {
        float g = mxw[0][threadIdx.x];
#pragma unroll
        for (int ww = 1; ww < 8; ww++) g = fmaxf(g, mxw[ww][threadIdx.x]);
        gmx[threadIdx.x] = g;
    }
    __syncthreads();

    float rsm[16];
#pragma unroll
    for (int r = 0; r < 16; r++) {
        float gm = gmx[rowv[r]];
        float e0 = __expf(acc[0][r] - gm);
        float e1 = __expf(acc[1][r] - gm);
        float e2 = __expf(acc[2][r] - gm);
        acc[0][r] = e0; acc[1][r] = e1; acc[2][r] = e2;
        rsm[r] = (e0 + e1) + e2;
    }
#pragma unroll
    for (int off = 16; off > 0; off >>= 1)
#pragma unroll
        for (int r = 0; r < 16; r++) rsm[r] += __shfl_xor(rsm[r], off);
    if (m == 0) {
#pragma unroll
        for (int r = 0; r < 16; r++) smw[w][rowv[r]] = rsm[r];
    }
    __syncthreads();
    if (threadIdx.x < 32) {
        float g = smw[0][threadIdx.x];
#pragma unroll
        for (int ww = 1; ww < 8; ww++) g += smw[ww][threadIdx.x];
        gsm[threadIdx.x] = g;
    }
    __syncthreads();

    // ---- phase 3: attn bf16 -> LDS, then PV --------------------------------
#pragma unroll
    for (int r = 0; r < 16; r++) {
        float inv = __builtin_amdgcn_rcpf(gsm[rowv[r]]);
#pragma unroll
        for (int t = 0; t < 3; t++)
            ap[rowv[r]][(w * 3 + t) * 32 + m] = f2bf(acc[t][r] * inv);
    }
    __syncthreads();

    const int s0 = w * 32;
    const unsigned short* Vp = uq + 2 * 786432 + head * 196608 + (s0 + m) * 768 + half * 8;
    f32x16 po;
#pragma unroll
    for (int r = 0; r < 16; r++) po[r] = 0.f;
#pragma unroll
    for (int kk = 0; kk < 48; kk++) {
        bf16x8 af = *(const bf16x8*)&ap[m][half * 8 + kk * 16];
        bf16x8 bf = *(const bf16x8*)(Vp + kk * 16);
        po = __builtin_amdgcn_mfma_f32_32x32x16_bf16(af, bf, po, 0, 0, 0);
    }
    float* O = ws + OFF_ATT + head * 196608;
#pragma unroll
    for (int r = 0; r < 16; r++) {
        O[(i0 + rowv[r]) * 256 + s0 + m] = po[r];
    }
}

// ---------------------------------------------------------------------------
// k_ffn: fused pointwise(3->12) + dwconv3x3 + gelu-gate + pointwise(6->3)
// + residual, f32 store. 32x16 pixel tiles (512 blocks), 34x18 halo in LDS.
// ---------------------------------------------------------------------------
struct FfnPtrs { const float* p[6]; };  // pi_w, pi_b, dw_w, dw_b, po_w, po_b

__global__ __launch_bounds__(256) void k_ffn(const float* __restrict__ ws,
                                             const float* __restrict__ x,
                                             FfnPtrs fp,
                                             float* __restrict__ out) {
    const int x0 = blockIdx.x * 32, y0 = blockIdx.y * 16;
    __shared__ float wsm[192];
    __shared__ float p[12][612];
    const int tid = threadIdx.x;
    if (tid < 36)       wsm[tid] = fp.p[0][tid];          // pi_w (12,3)
    else if (tid < 48)  wsm[tid] = fp.p[1][tid - 36];     // pi_b (12)
    else if (tid < 156) wsm[tid] = fp.p[2][tid - 48];     // dw_w (12,9)
    else if (tid < 168) wsm[tid] = fp.p[3][tid - 156];    // dw_b (12)
    else if (tid < 186) wsm[tid] = fp.p[4][tid - 168];    // po_w (3,6)
    else if (tid < 189) wsm[tid] = fp.p[5][tid - 186];    // po_b (3)
    __syncthreads();

    const float* A = ws + OFF_ATT;
    for (int i = tid; i < 612; i += 256) {
        int py = i / 34, px = i % 34;
        int gy = y0 + py - 1, gx = x0 + px - 1;
        bool in = ((unsigned)gy < 512u) && ((unsigned)gx < 512u);
        float a0 = 0.f, a1 = 0.f, a2 = 0.f;
        if (in) {
            int b = gy * 512 + gx;
            a0 = A[b]; a1 = A[262144 + b]; a2 = A[524288 + b];
        }
#pragma unroll
        for (int j = 0; j < 12; j++) {
            float t = in ? (wsm[36 + j] + wsm[j * 3] * a0 + wsm[j * 3 + 1] * a1
                            + wsm[j * 3 + 2] * a2)
                         : 0.f;
            p[j][i] = t;
        }
    }
    __syncthreads();

#pragma unroll
    for (int it = 0; it < 2; it++) {
        int pl = tid + it * 256;
        int ly = pl >> 5, lx = pl & 31;
        float z[12];
#pragma unroll
        for (int j = 0; j < 12; j++) {
            const float* dw = &wsm[48 + j * 9];
            const float* pr = &p[j][ly * 34 + lx];
            z[j] = wsm[156 + j]
                 + dw[0] * pr[0]  + dw[1] * pr[1]  + dw[2] * pr[2]
                 + dw[3] * pr[34] + dw[4] * pr[35] + dw[5] * pr[36]
                 + dw[6] * pr[68] + dw[7] * pr[69] + dw[8] * pr[70];
        }
        float g[6];
#pragma unroll
        for (int j = 0; j < 6; j++) {
            float xx = z[j];
            g[j] = 0.5f * xx * (1.f + erff(xx * 0.70710678118f)) * z[6 + j];
        }
        int b = (y0 + ly) * 512 + (x0 + lx);
#pragma unroll
        for (int co = 0; co < 3; co++) {
            float r = wsm[186 + co];
#pragma unroll
            for (int j = 0; j < 6; j++) r = fmaf(wsm[168 + co * 6 + j], g[j], r);
            r += x[co * 262144 + b];             // residual
            out[co * 262144 + b] = r;
        }
    }
}

// ---------------------------------------------------------------------------
extern "C" void kernel_launch(void* const* d_in, const int* in_sizes, int n_in,
                              void* d_out, int out_size, void* d_ws, size_t ws_size,
                              hipStream_t stream) {
    float* ws = (float*)d_ws;
    float* out = (float*)d_out;
    const float* x   = (const float*)d_in[0];
    const float* cw  = (const float*)d_in[1];
    const float* cb  = (const float*)d_in[2];
    const float* qw1 = (const float*)d_in[3];
    const float* kw1 = (const float*)d_in[7];
    const float* vw1 = (const float*)d_in[11];
    const float* temp= (const float*)d_in[15];

    MlpPtrs mp;
    mp.b1[0] = (const float*)d_in[4];  mp.w2[0] = (const float*)d_in[5];  mp.b2[0] = (const float*)d_in[6];
    mp.b1[1] = (const float*)d_in[8];  mp.w2[1] = (const float*)d_in[9];  mp.b2[1] = (const float*)d_in[10];
    mp.b1[2] = (const float*)d_in[12]; mp.w2[2] = (const float*)d_in[13]; mp.b2[2] = (const float*)d_in[14];

    FfnPtrs fp;
    for (int i = 0; i < 6; i++) fp.p[i] = (const float*)d_in[16 + i];

    k_pre <<<dim3(33, 3), 512, 0, stream>>>(x, qw1, kw1, vw1, cw, mp, ws);
    k_mlp <<<dim3(24, 8, 3), 256, 0, stream>>>(cb, mp, ws);
    k_attn<<<dim3(24, 4), 512, 0, stream>>>(temp, ws);
    k_ffn <<<dim3(16, 32), 256, 0, stream>>>(ws, x, fp, out);
}

// Round 6
// 208.654 us; speedup vs baseline: 1.0989x; 1.0989x over previous
//
#include <hip/hip_runtime.h>
#include <math.h>

// ---------------------------------------------------------------------------
// Restormer block, B=1 DIM=3 NC=512 HEADS=2 -> CT=768, NT=32, HID=6. f32 I/O.
//
// R19: revert R18's merged k_pre (96 blocks x serialized tasks = TLP collapse,
// 67us) back to R17's k_prep/k_corr/k_scat (576-block corr, 9 waves/CU).
// KEEP R18's k_mlp (double-buffered y1, one barrier per chunk, stage-2(t)
// overlapped with stage-1(t+1)) -- verified correct, isolates its delta vs
// the 209.3us R17 baseline. k_attn / k_ffn unchanged.
// ---------------------------------------------------------------------------

__device__ __forceinline__ float sigm(float s) {
    return __builtin_amdgcn_rcpf(1.f + __expf(-s));
}

using bf16x8 = __attribute__((ext_vector_type(8))) short;     // 8 bf16 (4 VGPRs)
using f16x8  = __attribute__((ext_vector_type(8))) _Float16;  // 8 f16  (4 VGPRs)
using f32x16 = __attribute__((ext_vector_type(16))) float;

__device__ __forceinline__ unsigned short f2bf(float f) {
    union { __bf16 h; unsigned short s; } u;
    u.h = (__bf16)f;                    // HW cvt, RNE
    return u.s;
}
__device__ __forceinline__ unsigned short f2h(float f) {
    union { _Float16 h; unsigned short s; } u;
    u.h = (_Float16)f;                  // HW cvt, RNE
    return u.s;
}

// ---- f32 workspace layout (element offsets) -------------------------------
// GB2: tap tensor, f16. u16 index = ((v*32 + n)*512 + h)*32 + k,
//      k = ci*9 + dy*3 + dx (k=27..31 zero; h-edge dy slots zero).
// T3 : compact taps, f16x4. uint2 index = ((v*3+ci)*512 + h)*32 + n,
//      halves = [a0, a1, a2, 0].
static constexpr int OFF_GB  = 0;          // 1,572,864 u16 = 786,432 f32
static constexpr int OFF_T3  = 786432;     // 294,912 f32 (2.25 MB)
static constexpr int OFF_S1  = 1081344;    // [3v][32] column sums of w1 (96)
static constexpr int OFF_CWB = 1081440;    // cw f16 pack [768c][32k] = 12288 f32
static constexpr int OFF_SC  = 1093728;    // w2 bf16 B-frag pack [3v][32hc][64lane][uint4] = 24576 f32
static constexpr int OFF_QKV = 1118304;    // ushort: Qb[4][768][256] | Kb | Vt[4][256][768] = 1179648 f32
static constexpr int OFF_ATT = 2297952;    // [4head][768][256] f32 == (3,512,512) flat
// total 3,084,384 floats = 12.3 MB

struct MlpPtrs {
    const float* b1[3];
    const float* w2[3];
    const float* b2[3];
};

// ---------------------------------------------------------------------------
// k_prep: S1[v][n] = sum_u w1v[u][n]; pack w2 into bf16 B-fragments at
// OFF_SC; pack cw into f16 A-rows at OFF_CWB. grid 51 x 256.
// ---------------------------------------------------------------------------
__global__ __launch_bounds__(256) void k_prep(const float* __restrict__ qw1,
                                              const float* __restrict__ kw1,
                                              const float* __restrict__ vw1,
                                              const float* __restrict__ cwp,
                                              MlpPtrs mp,
                                              float* __restrict__ ws) {
    int i = blockIdx.x * 256 + threadIdx.x;
    if (i < 6144) {                         // S1: 96 waves, shuffle-reduce
        int w = i >> 6, lane = i & 63;
        int v = w >> 5, n = w & 31;
        const float* w1p = (v == 0) ? qw1 : ((v == 1) ? kw1 : vw1);
        float s = 0.f;
#pragma unroll
        for (int k = 0; k < 8; k++) s += w1p[(lane + 64 * k) * 32 + n];
#pragma unroll
        for (int off = 32; off > 0; off >>= 1) s += __shfl_xor(s, off);
        if (lane == 0) ws[OFF_S1 + w] = s;
    } else if (i < 12288) {                 // w2 -> bf16 B-fragments
        int jj = i - 6144;                  // jj = v*2048 + hc*64 + lane
        int v = jj >> 11, r = jj & 2047;
        int hc = r >> 6, lane = r & 63;
        int o = lane & 31, half = lane >> 5;
        int H = hc * 16 + half * 8;
        const float* w2p = mp.w2[v];
        unsigned int d[4];
#pragma unroll
        for (int t = 0; t < 4; t++) {
            unsigned int lo = f2bf(w2p[(H + 2 * t) * 32 + o]);
            unsigned int hi = f2bf(w2p[(H + 2 * t + 1) * 32 + o]);
            d[t] = (hi << 16) | lo;
        }
        uint4* dst = (uint4*)(ws + OFF_SC);
        dst[jj] = make_uint4(d[0], d[1], d[2], d[3]);
    } else if (i < 13056) {                 // cw -> f16 A-rows [c][32k]
        int c = i - 12288;
        unsigned short* cwB = (unsigned short*)(ws + OFF_CWB);
#pragma unroll
        for (int k = 0; k < 32; k++)
            cwB[c * 32 + k] = (k < 27) ? f2h(cwp[c * 27 + k]) : (unsigned short)0;
    }
}

// ---------------------------------------------------------------------------
// k_corr: taps a_dx(ci, h, n) = sum_u x[ci][h][u] * w1v[u+1-dx][n], one
// coalesced uint2 store into T3 (halves [a0,a1,a2,0]).
// grid (64 hblk, 3 ci, 3 v), block 256 = 8 rows x 32 n.
// ---------------------------------------------------------------------------
__global__ __launch_bounds__(256) void k_corr(const float* __restrict__ x,
                                              const float* __restrict__ qw1,
                                              const float* __restrict__ kw1,
                                              const float* __restrict__ vw1,
                                              float* __restrict__ ws) {
    const int h0 = blockIdx.x * 8, ci = blockIdx.y, v = blockIdx.z;
    const int tid = threadIdx.x;
    __shared__ __align__(16) float ws1t[32 * 516];

    const float* w1f = (v == 0) ? qw1 : ((v == 1) ? kw1 : vw1);
    for (int i = tid; i < 4096; i += 256) {       // transpose-stage w1
        int n_ = i & 31, u = (i >> 5) * 4;
        float a = w1f[(u + 0) * 32 + n_];
        float b = w1f[(u + 1) * 32 + n_];
        float c = w1f[(u + 2) * 32 + n_];
        float d = w1f[(u + 3) * 32 + n_];
        *(float4*)&ws1t[n_ * 516 + u] = make_float4(a, b, c, d);
    }
    if (tid < 32) *(float4*)&ws1t[tid * 516 + 512] = make_float4(0.f, 0.f, 0.f, 0.f);
    __syncthreads();

    const int hp = tid >> 5, n = tid & 31;
    const float* xrow = x + ci * 262144 + (h0 + hp) * 512;
    float a0 = 0.f, a1 = 0.f, a2 = 0.f, pq = 0.f;
    float4 cq = *(float4*)&ws1t[n * 516];
#pragma unroll 4
    for (int k = 0; k < 128; k++) {
        float4 nq = *(float4*)&ws1t[n * 516 + 4 * k + 4];
        float4 x4 = *(const float4*)&xrow[4 * k];
        a1 = fmaf(x4.x, cq.x, a1); a1 = fmaf(x4.y, cq.y, a1);
        a1 = fmaf(x4.z, cq.z, a1); a1 = fmaf(x4.w, cq.w, a1);
        a0 = fmaf(x4.x, cq.y, a0); a0 = fmaf(x4.y, cq.z, a0);
        a0 = fmaf(x4.z, cq.w, a0); a0 = fmaf(x4.w, nq.x, a0);
        a2 = fmaf(x4.x, pq,   a2); a2 = fmaf(x4.y, cq.x, a2);
        a2 = fmaf(x4.z, cq.y, a2); a2 = fmaf(x4.w, cq.z, a2);
        pq = cq.w; cq = nq;
    }
    unsigned int lo = ((unsigned int)f2h(a1) << 16) | f2h(a0);
    unsigned int hi = (unsigned int)f2h(a2);            // high half = 0
    uint2* t3 = (uint2*)(ws + OFF_T3);
    t3[((size_t)(v * 3 + ci) * 512 + (h0 + hp)) * 32 + n] = make_uint2(lo, hi);
}

// ---------------------------------------------------------------------------
// k_scat: gather T3 -> GB2. Thread owns one (v, n, h): reads 9 guarded uint2
// (ci x dy, h_src = h+dy-1), assembles 32 k-halves in registers (all indices
// compile-time), writes one contiguous 64B (4x uint4). Writes every cell of
// GB2 including k/edge zero pads. grid (32 n, 3 v) x 256 thr (2 h each).
// ---------------------------------------------------------------------------
__global__ __launch_bounds__(256) void k_scat(float* __restrict__ ws) {
    const int n = blockIdx.x, v = blockIdx.y;
    const uint2* t3 = (const uint2*)(ws + OFF_T3);
    uint4* gb = (uint4*)ws;                                  // OFF_GB = 0

#pragma unroll
    for (int it = 0; it < 2; it++) {
        const int h = threadIdx.x + it * 256;
        union { unsigned short ks[32]; uint4 q[4]; } o;
#pragma unroll
        for (int t = 0; t < 4; t++) o.q[t] = make_uint4(0u, 0u, 0u, 0u);
#pragma unroll
        for (int ci = 0; ci < 3; ci++)
#pragma unroll
            for (int dy = 0; dy < 3; dy++) {
                const int hs = h + dy - 1;
                uint2 t2 = make_uint2(0u, 0u);
                if ((unsigned)hs < 512u)
                    t2 = t3[((size_t)(v * 3 + ci) * 512 + hs) * 32 + n];
                const int k = ci * 9 + dy * 3;
                o.ks[k]     = (unsigned short)(t2.x & 0xffffu);        // a0
                o.ks[k + 1] = (unsigned short)(t2.x >> 16);            // a1
                o.ks[k + 2] = (unsigned short)(t2.y & 0xffffu);        // a2
            }
        const size_t base = ((size_t)(v * 32 + n) * 512 + h) * 4;      // uint4 units
#pragma unroll
        for (int t = 0; t < 4; t++) gb[base + t] = o.q[t];
    }
}

// ---------------------------------------------------------------------------
// k_mlp: fused MFMA stage-1 + stage-2, double-buffered + pipelined (R18).
// Block = 32 c x 4 n x 512 h, 256 thr = 4 waves (wave w: n_l = w in stage-1,
// M-tile w in stage-2). One barrier per 32-h chunk: after BAR, stage-2(t)
// (ds_read + 2 bf16 MFMA) and stage-1(t+1) (2 f16 MFMA + sigmoid + LDS
// write to the other buffer) issue together. GB2/w2 frags prefetched +1.
// grid (24 ctile, 8 nquad, 3 v) = 576 blocks.
// ---------------------------------------------------------------------------
__global__ __launch_bounds__(256) void k_mlp(const float* __restrict__ cbp,
                                             MlpPtrs mp, float* __restrict__ ws) {
    const int v = blockIdx.z;
    const int c0 = blockIdx.x * 32;
    const int n0 = blockIdx.y * 4;
    const int tid = threadIdx.x;
    const int w = tid >> 6, lane = tid & 63;
    const int m = lane & 31, half = lane >> 5;

    __shared__ __align__(16) unsigned short y1t[2][4096];   // 2 x 8 KB, swizzled

    const unsigned short* cwB = (const unsigned short*)(ws + OFF_CWB);
    const f16x8 afA0 = *(const f16x8*)(cwB + (c0 + m) * 32 + half * 8);
    const f16x8 afA1 = *(const f16x8*)(cwB + (c0 + m) * 32 + 16 + half * 8);

    const uint4* w2pk = (const uint4*)(ws + OFF_SC) + (size_t)v * 2048 + lane;

    int rowv[16];
#pragma unroll
    for (int r = 0; r < 16; r++) rowv[r] = (r & 3) + 8 * (r >> 2) + 4 * half;

    const float b1n = mp.b1[v][n0 + w];
    const float s1n = ws[OFF_S1 + v * 32 + n0 + w];
    float bases[16];
#pragma unroll
    for (int r = 0; r < 16; r++)
        bases[r] = b1n + cbp[c0 + rowv[r]] * s1n;

    const unsigned short* gbv = (const unsigned short*)ws
        + ((size_t)(v * 32 + n0 + w) * 512) * 32;

    f32x16 acc;
#pragma unroll
    for (int r = 0; r < 16; r++) acc[r] = 0.f;

    // stage-2 read addresses (fixed per thread)
    const int row2 = w * 32 + m;
    const int swz2 = (row2 & 7) << 4;
    const int byte0 = (row2 * 64 + half * 16) ^ swz2;
    const int byte1 = (row2 * 64 + 32 + half * 16) ^ swz2;

    // ---- prologue: chunk 0 stage-1 into buf0 ----
    {
        f16x8 cb0 = *(const f16x8*)(gbv + (size_t)m * 32 + half * 8);
        f16x8 cb1 = *(const f16x8*)(gbv + (size_t)m * 32 + 16 + half * 8);
        f32x16 s1a;
#pragma unroll
        for (int r = 0; r < 16; r++) s1a[r] = 0.f;
        s1a = __builtin_amdgcn_mfma_f32_32x32x16_f16(afA0, cb0, s1a, 0, 0, 0);
        s1a = __builtin_amdgcn_mfma_f32_32x32x16_f16(afA1, cb1, s1a, 0, 0, 0);
#pragma unroll
        for (int r = 0; r < 16; r++) {
            float y = sigm(s1a[r] + bases[r]);
            int row = rowv[r] * 4 + w;
            int byte = (row * 64 + m * 2) ^ ((row & 7) << 4);
            *(unsigned short*)((char*)y1t[0] + byte) = f2bf(y);
        }
    }
    // prefetch chunk 1 GB2 frags + chunk 0/1 w2 frags
    f16x8 nb0 = *(const f16x8*)(gbv + (size_t)(32 + m) * 32 + half * 8);
    f16x8 nb1 = *(const f16x8*)(gbv + (size_t)(32 + m) * 32 + 16 + half * 8);
    uint4 cw0 = w2pk[0],   cw1 = w2pk[64];
    uint4 nw0 = w2pk[128], nw1 = w2pk[192];

    for (int t = 0; t < 16; t++) {
        __syncthreads();
        // stage-2(t) from buf[t&1]
        {
            bf16x8 a0 = *(const bf16x8*)((char*)y1t[t & 1] + byte0);
            bf16x8 a1 = *(const bf16x8*)((char*)y1t[t & 1] + byte1);
            union { uint4 u; bf16x8 b; } u0, u1;
            u0.u = cw0; u1.u = cw1;
            acc = __builtin_amdgcn_mfma_f32_32x32x16_bf16(a0, u0.b, acc, 0, 0, 0);
            acc = __builtin_amdgcn_mfma_f32_32x32x16_bf16(a1, u1.b, acc, 0, 0, 0);
        }
        // stage-1(t+1) into buf[(t+1)&1]
        if (t < 15) {
            f32x16 s1a;
#pragma unroll
            for (int r = 0; r < 16; r++) s1a[r] = 0.f;
            s1a = __builtin_amdgcn_mfma_f32_32x32x16_f16(afA0, nb0, s1a, 0, 0, 0);
            s1a = __builtin_amdgcn_mfma_f32_32x32x16_f16(afA1, nb1, s1a, 0, 0, 0);
            f16x8 pb0, pb1; uint4 pw0, pw1;
            if (t < 14) {                       // prefetch chunk t+2
                const size_t nbo = (size_t)((t + 2) * 32 + m) * 32;
                pb0 = *(const f16x8*)(gbv + nbo + half * 8);
                pb1 = *(const f16x8*)(gbv + nbo + 16 + half * 8);
                pw0 = w2pk[(t + 2) * 128];
                pw1 = w2pk[(t + 2) * 128 + 64];
            }
#pragma unroll
            for (int r = 0; r < 16; r++) {
                float y = sigm(s1a[r] + bases[r]);
                int row = rowv[r] * 4 + w;
                int byte = (row * 64 + m * 2) ^ ((row & 7) << 4);
                *(unsigned short*)((char*)y1t[(t + 1) & 1] + byte) = f2bf(y);
            }
            cw0 = nw0; cw1 = nw1;
            if (t < 14) { nb0 = pb0; nb1 = pb1; nw0 = pw0; nw1 = pw1; }
        }
    }

    // epilogue
    const float b2v = mp.b2[v][m];                   // o = m
    unsigned short* uq = (unsigned short*)(ws + OFF_QKV);
#pragma unroll
    for (int r = 0; r < 16; r++) {
        int rowg = w * 32 + rowv[r];
        int c  = c0 + (rowg >> 2);
        int ny = n0 + (rowg & 3);
        float mm = sigm(acc[r] + b2v);
        int head = ((m & 1) << 1) | (ny & 1);
        int sidx = ((m >> 1) << 4) | (ny >> 1);
        if (v < 2)  uq[v * 786432 + head * 196608 + c * 256 + sidx] = f2bf(mm);
        else        uq[2 * 786432 + head * 196608 + sidx * 768 + c] = f2bf(mm);
    }
}

// ---------------------------------------------------------------------------
// k_attn: fused QK^T * temp -> softmax -> @V for one (head, 32-row band).
// Block 512 = 8 waves. grid (24 iband, 4 head).
// ---------------------------------------------------------------------------
__global__ __launch_bounds__(512) void k_attn(const float* __restrict__ tempr,
                                              float* __restrict__ ws) {
    const unsigned short* uq = (const unsigned short*)(ws + OFF_QKV);
    const int head = blockIdx.y;
    const int i0 = blockIdx.x * 32;
    const int w = threadIdx.x >> 6, lane = threadIdx.x & 63;
    const int m = lane & 31, half = lane >> 5;

    __shared__ __align__(16) unsigned short ap[32][776];   // attn bf16, padded
    __shared__ float mxw[8][32];
    __shared__ float smw[8][32];
    __shared__ float gmx[32];
    __shared__ float gsm[32];

    const float temp = tempr[head];
    const unsigned short* Qp = uq + head * 196608 + (i0 + m) * 256 + half * 8;

    // ---- phase 1: QK^T for 3 j-tiles --------------------------------------
    f32x16 acc[3];
#pragma unroll
    for (int t = 0; t < 3; t++)
#pragma unroll
        for (int r = 0; r < 16; r++) acc[t][r] = 0.f;
#pragma unroll
    for (int t = 0; t < 3; t++) {
        const int j0 = (w * 3 + t) * 32;
        const unsigned short* Kp = uq + 786432 + head * 196608 + (j0 + m) * 256 + half * 8;
#pragma unroll
        for (int kk = 0; kk < 16; kk++) {
            bf16x8 af = *(const bf16x8*)(Qp + kk * 16);
            bf16x8 bf = *(const bf16x8*)(Kp + kk * 16);
            acc[t] = __builtin_amdgcn_mfma_f32_32x32x16_bf16(af, bf, acc[t], 0, 0, 0);
        }
    }
#pragma unroll
    for (int t = 0; t < 3; t++)
#pragma unroll
        for (int r = 0; r < 16; r++) acc[t][r] *= temp;

    // ---- phase 2: block softmax -------------------------------------------
    int rowv[16];
#pragma unroll
    for (int r = 0; r < 16; r++) rowv[r] = (r & 3) + 8 * (r >> 2) + 4 * half;

    float rmx[16];
#pragma unroll
    for (int r = 0; r < 16; r++)
        rmx[r] = fmaxf(fmaxf(acc[0][r], acc[1][r]), acc[2][r]);
#pragma unroll
    for (int off = 16; off > 0; off >>= 1)
#pragma unroll
        for (int r = 0; r < 16; r++) rmx[r] = fmaxf(rmx[r], __shfl_xor(rmx[r], off));
    if (m == 0) {
#pragma unroll
        for (int r = 0; r < 16; r++) mxw[w][rowv[r]] = rmx[r];
    }
    __syncthreads();
    if (threadIdx.x < 32) {
        float g = mxw[0][threadIdx.x];
#pragma unroll
        for (int ww = 1; ww < 8; ww++) g = fmaxf(g, mxw[ww][threadIdx.x]);
        gmx[threadIdx.x] = g;
    }
    __syncthreads();

    float rsm[16];
#pragma unroll
    for (int r = 0; r < 16; r++) {
        float gm = gmx[rowv[r]];
        float e0 = __expf(acc[0][r] - gm);
        float e1 = __expf(acc[1][r] - gm);
        float e2 = __expf(acc[2][r] - gm);
        acc[0][r] = e0; acc[1][r] = e1; acc[2][r] = e2;
        rsm[r] = (e0 + e1) + e2;
    }
#pragma unroll
    for (int off = 16; off > 0; off >>= 1)
#pragma unroll
        for (int r = 0; r < 16; r++) rsm[r] += __shfl_xor(rsm[r], off);
    if (m == 0) {
#pragma unroll
        for (int r = 0; r < 16; r++) smw[w][rowv[r]] = rsm[r];
    }
    __syncthreads();
    if (threadIdx.x < 32) {
        float g = smw[0][threadIdx.x];
#pragma unroll
        for (int ww = 1; ww < 8; ww++) g += smw[ww][threadIdx.x];
        gsm[threadIdx.x] = g;
    }
    __syncthreads();

    // ---- phase 3: attn bf16 -> LDS, then PV --------------------------------
#pragma unroll
    for (int r = 0; r < 16; r++) {
        float inv = __builtin_amdgcn_rcpf(gsm[rowv[r]]);
#pragma unroll
        for (int t = 0; t < 3; t++)
            ap[rowv[r]][(w * 3 + t) * 32 + m] = f2bf(acc[t][r] * inv);
    }
    __syncthreads();

    const int s0 = w * 32;
    const unsigned short* Vp = uq + 2 * 786432 + head * 196608 + (s0 + m) * 768 + half * 8;
    f32x16 po;
#pragma unroll
    for (int r = 0; r < 16; r++) po[r] = 0.f;
#pragma unroll
    for (int kk = 0; kk < 48; kk++) {
        bf16x8 af = *(const bf16x8*)&ap[m][half * 8 + kk * 16];
        bf16x8 bf = *(const bf16x8*)(Vp + kk * 16);
        po = __builtin_amdgcn_mfma_f32_32x32x16_bf16(af, bf, po, 0, 0, 0);
    }
    float* O = ws + OFF_ATT + head * 196608;
#pragma unroll
    for (int r = 0; r < 16; r++) {
        O[(i0 + rowv[r]) * 256 + s0 + m] = po[r];
    }
}

// ---------------------------------------------------------------------------
// k_ffn: fused pointwise(3->12) + dwconv3x3 + gelu-gate + pointwise(6->3)
// + residual, f32 store. 32x16 pixel tiles (512 blocks), 34x18 halo in LDS.
// ---------------------------------------------------------------------------
struct FfnPtrs { const float* p[6]; };  // pi_w, pi_b, dw_w, dw_b, po_w, po_b

__global__ __launch_bounds__(256) void k_ffn(const float* __restrict__ ws,
                                             const float* __restrict__ x,
                                             FfnPtrs fp,
                                             float* __restrict__ out) {
    const int x0 = blockIdx.x * 32, y0 = blockIdx.y * 16;
    __shared__ float wsm[192];
    __shared__ float p[12][612];
    const int tid = threadIdx.x;
    if (tid < 36)       wsm[tid] = fp.p[0][tid];          // pi_w (12,3)
    else if (tid < 48)  wsm[tid] = fp.p[1][tid - 36];     // pi_b (12)
    else if (tid < 156) wsm[tid] = fp.p[2][tid - 48];     // dw_w (12,9)
    else if (tid < 168) wsm[tid] = fp.p[3][tid - 156];    // dw_b (12)
    else if (tid < 186) wsm[tid] = fp.p[4][tid - 168];    // po_w (3,6)
    else if (tid < 189) wsm[tid] = fp.p[5][tid - 186];    // po_b (3)
    __syncthreads();

    const float* A = ws + OFF_ATT;
    for (int i = tid; i < 612; i += 256) {
        int py = i / 34, px = i % 34;
        int gy = y0 + py - 1, gx = x0 + px - 1;
        bool in = ((unsigned)gy < 512u) && ((unsigned)gx < 512u);
        float a0 = 0.f, a1 = 0.f, a2 = 0.f;
        if (in) {
            int b = gy * 512 + gx;
            a0 = A[b]; a1 = A[262144 + b]; a2 = A[524288 + b];
        }
#pragma unroll
        for (int j = 0; j < 12; j++) {
            float t = in ? (wsm[36 + j] + wsm[j * 3] * a0 + wsm[j * 3 + 1] * a1
                            + wsm[j * 3 + 2] * a2)
                         : 0.f;
            p[j][i] = t;
        }
    }
    __syncthreads();

#pragma unroll
    for (int it = 0; it < 2; it++) {
        int pl = tid + it * 256;
        int ly = pl >> 5, lx = pl & 31;
        float z[12];
#pragma unroll
        for (int j = 0; j < 12; j++) {
            const float* dw = &wsm[48 + j * 9];
            const float* pr = &p[j][ly * 34 + lx];
            z[j] = wsm[156 + j]
                 + dw[0] * pr[0]  + dw[1] * pr[1]  + dw[2] * pr[2]
                 + dw[3] * pr[34] + dw[4] * pr[35] + dw[5] * pr[36]
                 + dw[6] * pr[68] + dw[7] * pr[69] + dw[8] * pr[70];
        }
        float g[6];
#pragma unroll
        for (int j = 0; j < 6; j++) {
            float xx = z[j];
            g[j] = 0.5f * xx * (1.f + erff(xx * 0.70710678118f)) * z[6 + j];
        }
        int b = (y0 + ly) * 512 + (x0 + lx);
#pragma unroll
        for (int co = 0; co < 3; co++) {
            float r = wsm[186 + co];
#pragma unroll
            for (int j = 0; j < 6; j++) r = fmaf(wsm[168 + co * 6 + j], g[j], r);
            r += x[co * 262144 + b];             // residual
            out[co * 262144 + b] = r;
        }
    }
}

// ---------------------------------------------------------------------------
extern "C" void kernel_launch(void* const* d_in, const int* in_sizes, int n_in,
                              void* d_out, int out_size, void* d_ws, size_t ws_size,
                              hipStream_t stream) {
    float* ws = (float*)d_ws;
    float* out = (float*)d_out;
    const float* x   = (const float*)d_in[0];
    const float* cw  = (const float*)d_in[1];
    const float* cb  = (const float*)d_in[2];
    const float* qw1 = (const float*)d_in[3];
    const float* kw1 = (const float*)d_in[7];
    const float* vw1 = (const float*)d_in[11];
    const float* temp= (const float*)d_in[15];

    MlpPtrs mp;
    mp.b1[0] = (const float*)d_in[4];  mp.w2[0] = (const float*)d_in[5];  mp.b2[0] = (const float*)d_in[6];
    mp.b1[1] = (const float*)d_in[8];  mp.w2[1] = (const float*)d_in[9];  mp.b2[1] = (const float*)d_in[10];
    mp.b1[2] = (const float*)d_in[12]; mp.w2[2] = (const float*)d_in[13]; mp.b2[2] = (const float*)d_in[14];

    FfnPtrs fp;
    for (int i = 0; i < 6; i++) fp.p[i] = (const float*)d_in[16 + i];

    k_prep<<<51, 256, 0, stream>>>(qw1, kw1, vw1, cw, mp, ws);
    k_corr<<<dim3(64, 3, 3), 256, 0, stream>>>(x, qw1, kw1, vw1, ws);
    k_scat<<<dim3(32, 3), 256, 0, stream>>>(ws);
    k_mlp <<<dim3(24, 8, 3), 256, 0, stream>>>(cb, mp, ws);
    k_attn<<<dim3(24, 4), 512, 0, stream>>>(temp, ws);
    k_ffn <<<dim3(16, 32), 256, 0, stream>>>(ws, x, fp, out);
}

// Round 7
// 202.209 us; speedup vs baseline: 1.1339x; 1.0319x over previous
//
#include <hip/hip_runtime.h>
#include <math.h>

// ---------------------------------------------------------------------------
// Restormer block, B=1 DIM=3 NC=512 HEADS=2 -> CT=768, NT=32, HID=6. f32 I/O.
//
// R20: (a) k_mlp barrier-free: each wave owns an independent (32c x 1n x 512h)
// pipeline; stage-1 -> stage-2 transpose goes through a WAVE-PRIVATE 2KB LDS
// tile (same-wave write->read ordered by lgkmcnt, zero __syncthreads).
// (b) k_corr ws1t stride 516 -> 524: 8-way -> 4-way LDS bank conflicts
// (R18 counters: 9.4M conflict cycles on this exact loop).
// (c) k_prep merged into k_corr (k_cp, 627 blocks) -> one fewer launch.
// k_scat / k_attn / k_ffn unchanged from R19.
// ---------------------------------------------------------------------------

__device__ __forceinline__ float sigm(float s) {
    return __builtin_amdgcn_rcpf(1.f + __expf(-s));
}

using bf16x8 = __attribute__((ext_vector_type(8))) short;     // 8 bf16 (4 VGPRs)
using f16x8  = __attribute__((ext_vector_type(8))) _Float16;  // 8 f16  (4 VGPRs)
using f32x16 = __attribute__((ext_vector_type(16))) float;

__device__ __forceinline__ unsigned short f2bf(float f) {
    union { __bf16 h; unsigned short s; } u;
    u.h = (__bf16)f;                    // HW cvt, RNE
    return u.s;
}
__device__ __forceinline__ unsigned short f2h(float f) {
    union { _Float16 h; unsigned short s; } u;
    u.h = (_Float16)f;                  // HW cvt, RNE
    return u.s;
}

// ---- f32 workspace layout (element offsets) -------------------------------
// GB2: tap tensor, f16. u16 index = ((v*32 + n)*512 + h)*32 + k,
//      k = ci*9 + dy*3 + dx (k=27..31 zero; h-edge dy slots zero).
// T3 : compact taps, f16x4. uint2 index = ((v*3+ci)*512 + h)*32 + n,
//      halves = [a0, a1, a2, 0].
static constexpr int OFF_GB  = 0;          // 1,572,864 u16 = 786,432 f32
static constexpr int OFF_T3  = 786432;     // 294,912 f32 (2.25 MB)
static constexpr int OFF_S1  = 1081344;    // [3v][32] column sums of w1 (96)
static constexpr int OFF_CWB = 1081440;    // cw f16 pack [768c][32k] = 12288 f32
static constexpr int OFF_SC  = 1093728;    // w2 bf16 B-frag pack [3v][32hc][64lane][uint4] = 24576 f32
static constexpr int OFF_QKV = 1118304;    // ushort: Qb[4][768][256] | Kb | Vt[4][256][768] = 1179648 f32
static constexpr int OFF_ATT = 2297952;    // [4head][768][256] f32 == (3,512,512) flat
// total 3,084,384 floats = 12.3 MB

struct MlpPtrs {
    const float* b1[3];
    const float* w2[3];
    const float* b2[3];
};

// ---------------------------------------------------------------------------
// k_cp: merged prep + corr. grid 627 x 256.
// Blocks 0..575: corr — taps a_dx(ci,h,n) = sum_u x[ci][h][u]*w1v[u+1-dx][n],
//   one coalesced uint2 store into T3. Decode: hblk = b%64, ci=(b/64)%3,
//   v=b/192. ws1t stride 524 (4-way min bank conflicts on b128 reads).
// Blocks 576..626: prep — S1 sums, w2 bf16 B-frags, cw f16 A-rows.
// ---------------------------------------------------------------------------
__global__ __launch_bounds__(256) void k_cp(const float* __restrict__ x,
                                            const float* __restrict__ qw1,
                                            const float* __restrict__ kw1,
                                            const float* __restrict__ vw1,
                                            const float* __restrict__ cwp,
                                            MlpPtrs mp,
                                            float* __restrict__ ws) {
    const int tid = threadIdx.x;
    if (blockIdx.x >= 576) {               // ---- prep tasks ----
        int i = (blockIdx.x - 576) * 256 + tid;   // 0..13055
        if (i < 6144) {                     // S1: 96 waves, shuffle-reduce
            int w = i >> 6, lane = i & 63;
            int v = w >> 5, n = w & 31;
            const float* w1p = (v == 0) ? qw1 : ((v == 1) ? kw1 : vw1);
            float s = 0.f;
#pragma unroll
            for (int k = 0; k < 8; k++) s += w1p[(lane + 64 * k) * 32 + n];
#pragma unroll
            for (int off = 32; off > 0; off >>= 1) s += __shfl_xor(s, off);
            if (lane == 0) ws[OFF_S1 + w] = s;
        } else if (i < 12288) {             // w2 -> bf16 B-fragments
            int jj = i - 6144;              // jj = v*2048 + hc*64 + lane
            int v = jj >> 11, r = jj & 2047;
            int hc = r >> 6, lane = r & 63;
            int o = lane & 31, half = lane >> 5;
            int H = hc * 16 + half * 8;
            const float* w2p = mp.w2[v];
            unsigned int d[4];
#pragma unroll
            for (int t = 0; t < 4; t++) {
                unsigned int lo = f2bf(w2p[(H + 2 * t) * 32 + o]);
                unsigned int hi = f2bf(w2p[(H + 2 * t + 1) * 32 + o]);
                d[t] = (hi << 16) | lo;
            }
            uint4* dst = (uint4*)(ws + OFF_SC);
            dst[jj] = make_uint4(d[0], d[1], d[2], d[3]);
        } else if (i < 13056) {             // cw -> f16 A-rows [c][32k]
            int c = i - 12288;
            unsigned short* cwB = (unsigned short*)(ws + OFF_CWB);
#pragma unroll
            for (int k = 0; k < 32; k++)
                cwB[c * 32 + k] = (k < 27) ? f2h(cwp[c * 27 + k]) : (unsigned short)0;
        }
        return;
    }

    // ---- corr ----
    const int b = blockIdx.x;
    const int h0 = (b & 63) * 8;
    const int ci = (b >> 6) % 3;
    const int v  = b / 192;
    __shared__ __align__(16) float ws1t[32 * 524];          // 67 KB, stride 524

    const float* w1f = (v == 0) ? qw1 : ((v == 1) ? kw1 : vw1);
    for (int i = tid; i < 4096; i += 256) {       // transpose-stage w1
        int n_ = i & 31, u = (i >> 5) * 4;
        float a = w1f[(u + 0) * 32 + n_];
        float bb = w1f[(u + 1) * 32 + n_];
        float c = w1f[(u + 2) * 32 + n_];
        float d = w1f[(u + 3) * 32 + n_];
        *(float4*)&ws1t[n_ * 524 + u] = make_float4(a, bb, c, d);
    }
    if (tid < 32) *(float4*)&ws1t[tid * 524 + 512] = make_float4(0.f, 0.f, 0.f, 0.f);
    __syncthreads();

    const int hp = tid >> 5, n = tid & 31;
    const float* xrow = x + ci * 262144 + (h0 + hp) * 512;
    float a0 = 0.f, a1 = 0.f, a2 = 0.f, pq = 0.f;
    float4 cq = *(float4*)&ws1t[n * 524];
#pragma unroll 4
    for (int k = 0; k < 128; k++) {
        float4 nq = *(float4*)&ws1t[n * 524 + 4 * k + 4];
        float4 x4 = *(const float4*)&xrow[4 * k];
        a1 = fmaf(x4.x, cq.x, a1); a1 = fmaf(x4.y, cq.y, a1);
        a1 = fmaf(x4.z, cq.z, a1); a1 = fmaf(x4.w, cq.w, a1);
        a0 = fmaf(x4.x, cq.y, a0); a0 = fmaf(x4.y, cq.z, a0);
        a0 = fmaf(x4.z, cq.w, a0); a0 = fmaf(x4.w, nq.x, a0);
        a2 = fmaf(x4.x, pq,   a2); a2 = fmaf(x4.y, cq.x, a2);
        a2 = fmaf(x4.z, cq.y, a2); a2 = fmaf(x4.w, cq.z, a2);
        pq = cq.w; cq = nq;
    }
    unsigned int lo = ((unsigned int)f2h(a1) << 16) | f2h(a0);
    unsigned int hi = (unsigned int)f2h(a2);            // high half = 0
    uint2* t3 = (uint2*)(ws + OFF_T3);
    t3[((size_t)(v * 3 + ci) * 512 + (h0 + hp)) * 32 + n] = make_uint2(lo, hi);
}

// ---------------------------------------------------------------------------
// k_scat: gather T3 -> GB2. Thread owns one (v, n, h): reads 9 guarded uint2
// (ci x dy, h_src = h+dy-1), assembles 32 k-halves in registers, writes one
// contiguous 64B. Writes every cell incl. zero pads. grid (32 n, 3 v) x 256.
// ---------------------------------------------------------------------------
__global__ __launch_bounds__(256) void k_scat(float* __restrict__ ws) {
    const int n = blockIdx.x, v = blockIdx.y;
    const uint2* t3 = (const uint2*)(ws + OFF_T3);
    uint4* gb = (uint4*)ws;                                  // OFF_GB = 0

#pragma unroll
    for (int it = 0; it < 2; it++) {
        const int h = threadIdx.x + it * 256;
        union { unsigned short ks[32]; uint4 q[4]; } o;
#pragma unroll
        for (int t = 0; t < 4; t++) o.q[t] = make_uint4(0u, 0u, 0u, 0u);
#pragma unroll
        for (int ci = 0; ci < 3; ci++)
#pragma unroll
            for (int dy = 0; dy < 3; dy++) {
                const int hs = h + dy - 1;
                uint2 t2 = make_uint2(0u, 0u);
                if ((unsigned)hs < 512u)
                    t2 = t3[((size_t)(v * 3 + ci) * 512 + hs) * 32 + n];
                const int k = ci * 9 + dy * 3;
                o.ks[k]     = (unsigned short)(t2.x & 0xffffu);        // a0
                o.ks[k + 1] = (unsigned short)(t2.x >> 16);            // a1
                o.ks[k + 2] = (unsigned short)(t2.y & 0xffffu);        // a2
            }
        const size_t base = ((size_t)(v * 32 + n) * 512 + h) * 4;      // uint4 units
#pragma unroll
        for (int t = 0; t < 4; t++) gb[base + t] = o.q[t];
    }
}

// ---------------------------------------------------------------------------
// k_mlp: barrier-free. Block 256 = 4 INDEPENDENT waves; wave w owns
// (32c tile, n = n0+w, all 512 h). Per 32-h chunk: stage-1 C[c][h] =
// cwB x GB2 (2x mfma f16) -> sigmoid -> bf16 into wave-private 2KB LDS
// tile (rows=c, swizzled) -> lgkmcnt -> A-frags (rows=c, k=h) ->
// stage-2 acc[c][o] += y1 x w2 (2x mfma bf16). No __syncthreads at all.
// GB2/w2 frags prefetched one chunk ahead.
// grid (24 ctile, 8 nquad, 3 v) = 576 blocks.
// ---------------------------------------------------------------------------
__global__ __launch_bounds__(256) void k_mlp(const float* __restrict__ cbp,
                                             MlpPtrs mp, float* __restrict__ ws) {
    const int v = blockIdx.z;
    const int c0 = blockIdx.x * 32;
    const int n0 = blockIdx.y * 4;
    const int tid = threadIdx.x;
    const int w = tid >> 6, lane = tid & 63;
    const int m = lane & 31, half = lane >> 5;

    __shared__ __align__(16) unsigned short y1t[4][1024];   // 2 KB per wave
    char* tb = (char*)&y1t[w][0];

    const unsigned short* cwB = (const unsigned short*)(ws + OFF_CWB);
    const f16x8 afA0 = *(const f16x8*)(cwB + (c0 + m) * 32 + half * 8);
    const f16x8 afA1 = *(const f16x8*)(cwB + (c0 + m) * 32 + 16 + half * 8);

    const uint4* w2pk = (const uint4*)(ws + OFF_SC) + (size_t)v * 2048 + lane;

    int rowv[16];
#pragma unroll
    for (int r = 0; r < 16; r++) rowv[r] = (r & 3) + 8 * (r >> 2) + 4 * half;

    const int nl = n0 + w;                           // this wave's n
    const float b1n = mp.b1[v][nl];
    const float s1n = ws[OFF_S1 + v * 32 + nl];
    float bases[16];
#pragma unroll
    for (int r = 0; r < 16; r++)
        bases[r] = b1n + cbp[c0 + rowv[r]] * s1n;

    const unsigned short* gbv = (const unsigned short*)ws
        + ((size_t)(v * 32 + nl) * 512) * 32;

    f32x16 acc;
#pragma unroll
    for (int r = 0; r < 16; r++) acc[r] = 0.f;

    // stage-2 read addresses (fixed per thread; row = c = m, same swizzle as write)
    const int byteA0 = (m * 64 + half * 16) ^ ((m & 7) << 4);
    const int byteA1 = (m * 64 + 32 + half * 16) ^ ((m & 7) << 4);

    // prefetch chunk 0
    f16x8 cb0 = *(const f16x8*)(gbv + (size_t)m * 32 + half * 8);
    f16x8 cb1 = *(const f16x8*)(gbv + (size_t)m * 32 + 16 + half * 8);
    uint4 cw0 = w2pk[0], cw1 = w2pk[64];

    for (int t = 0; t < 16; t++) {
        f16x8 nb0, nb1; uint4 nw0, nw1;
        if (t < 15) {                                // prefetch chunk t+1
            const size_t nbo = (size_t)((t + 1) * 32 + m) * 32;
            nb0 = *(const f16x8*)(gbv + nbo + half * 8);
            nb1 = *(const f16x8*)(gbv + nbo + 16 + half * 8);
            nw0 = w2pk[(t + 1) * 128];
            nw1 = w2pk[(t + 1) * 128 + 64];
        }
        // stage-1: C[c][h] for this chunk
        f32x16 s1a;
#pragma unroll
        for (int r = 0; r < 16; r++) s1a[r] = 0.f;
        s1a = __builtin_amdgcn_mfma_f32_32x32x16_f16(afA0, cb0, s1a, 0, 0, 0);
        s1a = __builtin_amdgcn_mfma_f32_32x32x16_f16(afA1, cb1, s1a, 0, 0, 0);
#pragma unroll
        for (int r = 0; r < 16; r++) {
            float y = sigm(s1a[r] + bases[r]);
            const int row = rowv[r];                 // c-row
            const int byte = (row * 64 + m * 2) ^ ((row & 7) << 4);
            *(unsigned short*)(tb + byte) = f2bf(y);
        }
        // same-wave LDS write -> read: drain DS queue, pin order
        asm volatile("s_waitcnt lgkmcnt(0)" ::: "memory");
        __builtin_amdgcn_sched_barrier(0);
        // stage-2: A rows = c, k = h
        {
            bf16x8 a0 = *(const bf16x8*)(tb + byteA0);
            bf16x8 a1 = *(const bf16x8*)(tb + byteA1);
            union { uint4 u; bf16x8 b; } u0, u1;
            u0.u = cw0; u1.u = cw1;
            acc = __builtin_amdgcn_mfma_f32_32x32x16_bf16(a0, u0.b, acc, 0, 0, 0);
            acc = __builtin_amdgcn_mfma_f32_32x32x16_bf16(a1, u1.b, acc, 0, 0, 0);
        }
        if (t < 15) { cb0 = nb0; cb1 = nb1; cw0 = nw0; cw1 = nw1; }
    }

    // epilogue: rows = c, o = m, n fixed per wave
    const float b2v = mp.b2[v][m];
    unsigned short* uq = (unsigned short*)(ws + OFF_QKV);
#pragma unroll
    for (int r = 0; r < 16; r++) {
        const int c  = c0 + rowv[r];
        const int ny = nl;
        float mm = sigm(acc[r] + b2v);
        int head = ((m & 1) << 1) | (ny & 1);
        int sidx = ((m >> 1) << 4) | (ny >> 1);
        if (v < 2)  uq[v * 786432 + head * 196608 + c * 256 + sidx] = f2bf(mm);
        else        uq[2 * 786432 + head * 196608 + sidx * 768 + c] = f2bf(mm);
    }
}

// ---------------------------------------------------------------------------
// k_attn: fused QK^T * temp -> softmax -> @V for one (head, 32-row band).
// Block 512 = 8 waves. grid (24 iband, 4 head). (unchanged)
// ---------------------------------------------------------------------------
__global__ __launch_bounds__(512) void k_attn(const float* __restrict__ tempr,
                                              float* __restrict__ ws) {
    const unsigned short* uq = (const unsigned short*)(ws + OFF_QKV);
    const int head = blockIdx.y;
    const int i0 = blockIdx.x * 32;
    const int w = threadIdx.x >> 6, lane = threadIdx.x & 63;
    const int m = lane & 31, half = lane >> 5;

    __shared__ __align__(16) unsigned short ap[32][776];   // attn bf16, padded
    __shared__ float mxw[8][32];
    __shared__ float smw[8][32];
    __shared__ float gmx[32];
    __shared__ float gsm[32];

    const float temp = tempr[head];
    const unsigned short* Qp = uq + head * 196608 + (i0 + m) * 256 + half * 8;

    // ---- phase 1: QK^T for 3 j-tiles --------------------------------------
    f32x16 acc[3];
#pragma unroll
    for (int t = 0; t < 3; t++)
#pragma unroll
        for (int r = 0; r < 16; r++) acc[t][r] = 0.f;
#pragma unroll
    for (int t = 0; t < 3; t++) {
        const int j0 = (w * 3 + t) * 32;
        const unsigned short* Kp = uq + 786432 + head * 196608 + (j0 + m) * 256 + half * 8;
#pragma unroll
        for (int kk = 0; kk < 16; kk++) {
            bf16x8 af = *(const bf16x8*)(Qp + kk * 16);
            bf16x8 bf = *(const bf16x8*)(Kp + kk * 16);
            acc[t] = __builtin_amdgcn_mfma_f32_32x32x16_bf16(af, bf, acc[t], 0, 0, 0);
        }
    }
#pragma unroll
    for (int t = 0; t < 3; t++)
#pragma unroll
        for (int r = 0; r < 16; r++) acc[t][r] *= temp;

    // ---- phase 2: block softmax -------------------------------------------
    int rowv[16];
#pragma unroll
    for (int r = 0; r < 16; r++) rowv[r] = (r & 3) + 8 * (r >> 2) + 4 * half;

    float rmx[16];
#pragma unroll
    for (int r = 0; r < 16; r++)
        rmx[r] = fmaxf(fmaxf(acc[0][r], acc[1][r]), acc[2][r]);
#pragma unroll
    for (int off = 16; off > 0; off >>= 1)
#pragma unroll
        for (int r = 0; r < 16; r++) rmx[r] = fmaxf(rmx[r], __shfl_xor(rmx[r], off));
    if (m == 0) {
#pragma unroll
        for (int r = 0; r < 16; r++) mxw[w][rowv[r]] = rmx[r];
    }
    __syncthreads();
    if (threadIdx.x < 32) {
        float g = mxw[0][threadIdx.x];
#pragma unroll
        for (int ww = 1; ww < 8; ww++) g = fmaxf(g, mxw[ww][threadIdx.x]);
        gmx[threadIdx.x] = g;
    }
    __syncthreads();

    float rsm[16];
#pragma unroll
    for (int r = 0; r < 16; r++) {
        float gm = gmx[rowv[r]];
        float e0 = __expf(acc[0][r] - gm);
        float e1 = __expf(acc[1][r] - gm);
        float e2 = __expf(acc[2][r] - gm);
        acc[0][r] = e0; acc[1][r] = e1; acc[2][r] = e2;
        rsm[r] = (e0 + e1) + e2;
    }
#pragma unroll
    for (int off = 16; off > 0; off >>= 1)
#pragma unroll
        for (int r = 0; r < 16; r++) rsm[r] += __shfl_xor(rsm[r], off);
    if (m == 0) {
#pragma unroll
        for (int r = 0; r < 16; r++) smw[w][rowv[r]] = rsm[r];
    }
    __syncthreads();
    if (threadIdx.x < 32) {
        float g = smw[0][threadIdx.x];
#pragma unroll
        for (int ww = 1; ww < 8; ww++) g += smw[ww][threadIdx.x];
        gsm[threadIdx.x] = g;
    }
    __syncthreads();

    // ---- phase 3: attn bf16 -> LDS, then PV --------------------------------
#pragma unroll
    for (int r = 0; r < 16; r++) {
        float inv = __builtin_amdgcn_rcpf(gsm[rowv[r]]);
#pragma unroll
        for (int t = 0; t < 3; t++)
            ap[rowv[r]][(w * 3 + t) * 32 + m] = f2bf(acc[t][r] * inv);
    }
    __syncthreads();

    const int s0 = w * 32;
    const unsigned short* Vp = uq + 2 * 786432 + head * 196608 + (s0 + m) * 768 + half * 8;
    f32x16 po;
#pragma unroll
    for (int r = 0; r < 16; r++) po[r] = 0.f;
#pragma unroll
    for (int kk = 0; kk < 48; kk++) {
        bf16x8 af = *(const bf16x8*)&ap[m][half * 8 + kk * 16];
        bf16x8 bf = *(const bf16x8*)(Vp + kk * 16);
        po = __builtin_amdgcn_mfma_f32_32x32x16_bf16(af, bf, po, 0, 0, 0);
    }
    float* O = ws + OFF_ATT + head * 196608;
#pragma unroll
    for (int r = 0; r < 16; r++) {
        O[(i0 + rowv[r]) * 256 + s0 + m] = po[r];
    }
}

// ---------------------------------------------------------------------------
// k_ffn: fused pointwise(3->12) + dwconv3x3 + gelu-gate + pointwise(6->3)
// + residual, f32 store. 32x16 pixel tiles (512 blocks), 34x18 halo in LDS.
// ---------------------------------------------------------------------------
struct FfnPtrs { const float* p[6]; };  // pi_w, pi_b, dw_w, dw_b, po_w, po_b

__global__ __launch_bounds__(256) void k_ffn(const float* __restrict__ ws,
                                             const float* __restrict__ x,
                                             FfnPtrs fp,
                                             float* __restrict__ out) {
    const int x0 = blockIdx.x * 32, y0 = blockIdx.y * 16;
    __shared__ float wsm[192];
    __shared__ float p[12][612];
    const int tid = threadIdx.x;
    if (tid < 36)       wsm[tid] = fp.p[0][tid];          // pi_w (12,3)
    else if (tid < 48)  wsm[tid] = fp.p[1][tid - 36];     // pi_b (12)
    else if (tid < 156) wsm[tid] = fp.p[2][tid - 48];     // dw_w (12,9)
    else if (tid < 168) wsm[tid] = fp.p[3][tid - 156];    // dw_b (12)
    else if (tid < 186) wsm[tid] = fp.p[4][tid - 168];    // po_w (3,6)
    else if (tid < 189) wsm[tid] = fp.p[5][tid - 186];    // po_b (3)
    __syncthreads();

    const float* A = ws + OFF_ATT;
    for (int i = tid; i < 612; i += 256) {
        int py = i / 34, px = i % 34;
        int gy = y0 + py - 1, gx = x0 + px - 1;
        bool in = ((unsigned)gy < 512u) && ((unsigned)gx < 512u);
        float a0 = 0.f, a1 = 0.f, a2 = 0.f;
        if (in) {
            int b = gy * 512 + gx;
            a0 = A[b]; a1 = A[262144 + b]; a2 = A[524288 + b];
        }
#pragma unroll
        for (int j = 0; j < 12; j++) {
            float t = in ? (wsm[36 + j] + wsm[j * 3] * a0 + wsm[j * 3 + 1] * a1
                            + wsm[j * 3 + 2] * a2)
                         : 0.f;
            p[j][i] = t;
        }
    }
    __syncthreads();

#pragma unroll
    for (int it = 0; it < 2; it++) {
        int pl = tid + it * 256;
        int ly = pl >> 5, lx = pl & 31;
        float z[12];
#pragma unroll
        for (int j = 0; j < 12; j++) {
            const float* dw = &wsm[48 + j * 9];
            const float* pr = &p[j][ly * 34 + lx];
            z[j] = wsm[156 + j]
                 + dw[0] * pr[0]  + dw[1] * pr[1]  + dw[2] * pr[2]
                 + dw[3] * pr[34] + dw[4] * pr[35] + dw[5] * pr[36]
                 + dw[6] * pr[68] + dw[7] * pr[69] + dw[8] * pr[70];
        }
        float g[6];
#pragma unroll
        for (int j = 0; j < 6; j++) {
            float xx = z[j];
            g[j] = 0.5f * xx * (1.f + erff(xx * 0.70710678118f)) * z[6 + j];
        }
        int b = (y0 + ly) * 512 + (x0 + lx);
#pragma unroll
        for (int co = 0; co < 3; co++) {
            float r = wsm[186 + co];
#pragma unroll
            for (int j = 0; j < 6; j++) r = fmaf(wsm[168 + co * 6 + j], g[j], r);
            r += x[co * 262144 + b];             // residual
            out[co * 262144 + b] = r;
        }
    }
}

// ---------------------------------------------------------------------------
extern "C" void kernel_launch(void* const* d_in, const int* in_sizes, int n_in,
                              void* d_out, int out_size, void* d_ws, size_t ws_size,
                              hipStream_t stream) {
    float* ws = (float*)d_ws;
    float* out = (float*)d_out;
    const float* x   = (const float*)d_in[0];
    const float* cw  = (const float*)d_in[1];
    const float* cb  = (const float*)d_in[2];
    const float* qw1 = (const float*)d_in[3];
    const float* kw1 = (const float*)d_in[7];
    const float* vw1 = (const float*)d_in[11];
    const float* temp= (const float*)d_in[15];

    MlpPtrs mp;
    mp.b1[0] = (const float*)d_in[4];  mp.w2[0] = (const float*)d_in[5];  mp.b2[0] = (const float*)d_in[6];
    mp.b1[1] = (const float*)d_in[8];  mp.w2[1] = (const float*)d_in[9];  mp.b2[1] = (const float*)d_in[10];
    mp.b1[2] = (const float*)d_in[12]; mp.w2[2] = (const float*)d_in[13]; mp.b2[2] = (const float*)d_in[14];

    FfnPtrs fp;
    for (int i = 0; i < 6; i++) fp.p[i] = (const float*)d_in[16 + i];

    k_cp  <<<627, 256, 0, stream>>>(x, qw1, kw1, vw1, cw, mp, ws);
    k_scat<<<dim3(32, 3), 256, 0, stream>>>(ws);
    k_mlp <<<dim3(24, 8, 3), 256, 0, stream>>>(cb, mp, ws);
    k_attn<<<dim3(24, 4), 512, 0, stream>>>(temp, ws);
    k_ffn <<<dim3(16, 32), 256, 0, stream>>>(ws, x, fp, out);
}

// Round 8
// 183.390 us; speedup vs baseline: 1.2503x; 1.1026x over previous
//
#include <hip/hip_runtime.h>
#include <math.h>

// ---------------------------------------------------------------------------
// Restormer block, B=1 DIM=3 NC=512 HEADS=2 -> CT=768, NT=32, HID=6. f32 I/O.
//
// R21: k_corr moved onto MFMA. The correlation a_dx[ci,h,n] =
// sum_u x[ci][h][u] * w1[u+1-dx][n] is a GEMM (M=h, N=(n,dx), K=u=512):
// k_prep packs 3 dx-shifted row-guarded f16 copies of w1 as B-fragments
// (W1T); k_corr converts x rows to f16 A-frags on the fly and does
// 3 MFMAs (dx 0..2) per K-step, 4-wave K-split + LDS reduce, then the
// SAME T3 uint2 stores as R20. k_scat / k_mlp (barrier-free R20) /
// k_attn / k_ffn unchanged.
// ---------------------------------------------------------------------------

__device__ __forceinline__ float sigm(float s) {
    return __builtin_amdgcn_rcpf(1.f + __expf(-s));
}

using bf16x8 = __attribute__((ext_vector_type(8))) short;     // 8 bf16 (4 VGPRs)
using f16x8  = __attribute__((ext_vector_type(8))) _Float16;  // 8 f16  (4 VGPRs)
using f32x16 = __attribute__((ext_vector_type(16))) float;

__device__ __forceinline__ unsigned short f2bf(float f) {
    union { __bf16 h; unsigned short s; } u;
    u.h = (__bf16)f;                    // HW cvt, RNE
    return u.s;
}
__device__ __forceinline__ unsigned short f2h(float f) {
    union { _Float16 h; unsigned short s; } u;
    u.h = (_Float16)f;                  // HW cvt, RNE
    return u.s;
}

// ---- f32 workspace layout (element offsets) -------------------------------
// GB2: tap tensor, f16. u16 index = ((v*32 + n)*512 + h)*32 + k,
//      k = ci*9 + dy*3 + dx (k=27..31 zero; h-edge dy slots zero).
// T3 : compact taps, f16x4. uint2 index = ((v*3+ci)*512 + h)*32 + n,
//      halves = [a0, a1, a2, -].
// W1T: w1 dx-shifted f16 B-frag pack, uint4 index = ((v*3+dx)*32+kk)*64+lane.
static constexpr int OFF_GB  = 0;          // 786,432 f32
static constexpr int OFF_T3  = 786432;     // 294,912 f32
static constexpr int OFF_S1  = 1081344;    // 96
static constexpr int OFF_CWB = 1081440;    // 12,288
static constexpr int OFF_SC  = 1093728;    // 24,576
static constexpr int OFF_W1T = 1118304;    // 73,728 f32 (18432 uint4)
static constexpr int OFF_QKV = 1192032;    // 1,179,648 f32 (ushort QKV)
static constexpr int OFF_ATT = 2371680;    // 786,432 f32 == (3,512,512) flat
// total 3,158,112 floats = 12.6 MB

struct MlpPtrs {
    const float* b1[3];
    const float* w2[3];
    const float* b2[3];
};

// ---------------------------------------------------------------------------
// k_prep: S1 sums; w2 bf16 B-frags; cw f16 A-rows; W1T dx-shifted f16
// B-frags (row-guarded: u' = u0+2t+{0,1}+1-dx outside [0,512) -> 0).
// grid 123 x 256.
// ---------------------------------------------------------------------------
__global__ __launch_bounds__(256) void k_prep(const float* __restrict__ qw1,
                                              const float* __restrict__ kw1,
                                              const float* __restrict__ vw1,
                                              const float* __restrict__ cwp,
                                              MlpPtrs mp,
                                              float* __restrict__ ws) {
    int i = blockIdx.x * 256 + threadIdx.x;
    if (i < 6144) {                         // S1: 96 waves, shuffle-reduce
        int w = i >> 6, lane = i & 63;
        int v = w >> 5, n = w & 31;
        const float* w1p = (v == 0) ? qw1 : ((v == 1) ? kw1 : vw1);
        float s = 0.f;
#pragma unroll
        for (int k = 0; k < 8; k++) s += w1p[(lane + 64 * k) * 32 + n];
#pragma unroll
        for (int off = 32; off > 0; off >>= 1) s += __shfl_xor(s, off);
        if (lane == 0) ws[OFF_S1 + w] = s;
    } else if (i < 12288) {                 // w2 -> bf16 B-fragments
        int jj = i - 6144;                  // jj = v*2048 + hc*64 + lane
        int v = jj >> 11, r = jj & 2047;
        int hc = r >> 6, lane = r & 63;
        int o = lane & 31, half = lane >> 5;
        int H = hc * 16 + half * 8;
        const float* w2p = mp.w2[v];
        unsigned int d[4];
#pragma unroll
        for (int t = 0; t < 4; t++) {
            unsigned int lo = f2bf(w2p[(H + 2 * t) * 32 + o]);
            unsigned int hi = f2bf(w2p[(H + 2 * t + 1) * 32 + o]);
            d[t] = (hi << 16) | lo;
        }
        uint4* dst = (uint4*)(ws + OFF_SC);
        dst[jj] = make_uint4(d[0], d[1], d[2], d[3]);
    } else if (i < 13056) {                 // cw -> f16 A-rows [c][32k]
        int c = i - 12288;
        unsigned short* cwB = (unsigned short*)(ws + OFF_CWB);
#pragma unroll
        for (int k = 0; k < 32; k++)
            cwB[c * 32 + k] = (k < 27) ? f2h(cwp[c * 27 + k]) : (unsigned short)0;
    } else if (i < 31488) {                 // W1T dx-shifted f16 B-frags
        int j = i - 13056;                  // j = v*6144 + dx*2048 + kk*64 + lane
        int v = j / 6144, rem = j % 6144;
        int dx = rem >> 11, rem2 = rem & 2047;
        int kk = rem2 >> 6, lane = rem2 & 63;
        int o = lane & 31, hf = lane >> 5;
        int u0 = kk * 16 + hf * 8;
        const float* w1p = (v == 0) ? qw1 : ((v == 1) ? kw1 : vw1);
        unsigned int d[4];
#pragma unroll
        for (int t = 0; t < 4; t++) {
            int r0 = u0 + 2 * t + 1 - dx;
            int r1 = r0 + 1;
            unsigned int lo = ((unsigned)r0 < 512u) ? f2h(w1p[r0 * 32 + o]) : 0u;
            unsigned int hi = ((unsigned)r1 < 512u) ? f2h(w1p[r1 * 32 + o]) : 0u;
            d[t] = (hi << 16) | lo;
        }
        uint4* dst = (uint4*)(ws + OFF_W1T);
        dst[j] = make_uint4(d[0], d[1], d[2], d[3]);
    }
}

// ---------------------------------------------------------------------------
// k_corr (MFMA): per block (32 h-rows, ci, v): 4 waves K-split (each 8
// K-steps of 16 u). Per step: x row -> f16 A-frag (2 float4 + cvt), 3
// coalesced uint4 B-frags (W1T), 3 MFMAs (dx 0..2). LDS cross-wave
// reduce; wave 0 stores T3 uint2 rows (same layout/values as R20).
// grid (16 htile, 3 ci, 3 v) = 144 blocks.
// ---------------------------------------------------------------------------
__global__ __launch_bounds__(256) void k_corr(const float* __restrict__ x,
                                              float* __restrict__ ws) {
    const int h0 = blockIdx.x * 32, ci = blockIdx.y, v = blockIdx.z;
    const int tid = threadIdx.x;
    const int ks = tid >> 6, lane = tid & 63;
    const int m = lane & 31, half = lane >> 5;
    __shared__ float red[3][3][16][64];     // 36 KB

    const uint4* w1t = (const uint4*)(ws + OFF_W1T) + (size_t)v * 6144 + lane;
    const float* xb = x + ci * 262144 + (h0 + m) * 512;

    f32x16 acc0, acc1, acc2;
#pragma unroll
    for (int r = 0; r < 16; r++) { acc0[r] = 0.f; acc1[r] = 0.f; acc2[r] = 0.f; }

#pragma unroll
    for (int s = 0; s < 8; s++) {
        const int kk = ks * 8 + s;
        const int u0 = kk * 16 + half * 8;
        float4 xa = *(const float4*)(xb + u0);
        float4 xc = *(const float4*)(xb + u0 + 4);
        f16x8 af;
        af[0] = (_Float16)xa.x; af[1] = (_Float16)xa.y;
        af[2] = (_Float16)xa.z; af[3] = (_Float16)xa.w;
        af[4] = (_Float16)xc.x; af[5] = (_Float16)xc.y;
        af[6] = (_Float16)xc.z; af[7] = (_Float16)xc.w;
        union { uint4 u; f16x8 h; } b0, b1, b2;
        b0.u = w1t[(size_t)(0 * 32 + kk) * 64];
        b1.u = w1t[(size_t)(1 * 32 + kk) * 64];
        b2.u = w1t[(size_t)(2 * 32 + kk) * 64];
        acc0 = __builtin_amdgcn_mfma_f32_32x32x16_f16(af, b0.h, acc0, 0, 0, 0);
        acc1 = __builtin_amdgcn_mfma_f32_32x32x16_f16(af, b1.h, acc1, 0, 0, 0);
        acc2 = __builtin_amdgcn_mfma_f32_32x32x16_f16(af, b2.h, acc2, 0, 0, 0);
    }

    int rowv[16];
#pragma unroll
    for (int r = 0; r < 16; r++) rowv[r] = (r & 3) + 8 * (r >> 2) + 4 * half;

    if (ks > 0) {
#pragma unroll
        for (int r = 0; r < 16; r++) {
            red[ks - 1][0][r][lane] = acc0[r];
            red[ks - 1][1][r][lane] = acc1[r];
            red[ks - 1][2][r][lane] = acc2[r];
        }
    }
    __syncthreads();
    if (ks == 0) {
        uint2* t3 = (uint2*)(ws + OFF_T3);
#pragma unroll
        for (int r = 0; r < 16; r++) {
            float a0 = acc0[r] + red[0][0][r][lane] + red[1][0][r][lane] + red[2][0][r][lane];
            float a1 = acc1[r] + red[0][1][r][lane] + red[1][1][r][lane] + red[2][1][r][lane];
            float a2 = acc2[r] + red[0][2][r][lane] + red[1][2][r][lane] + red[2][2][r][lane];
            const int h = h0 + rowv[r];
            unsigned int lo = ((unsigned int)f2h(a1) << 16) | f2h(a0);
            unsigned int hi = (unsigned int)f2h(a2);
            t3[((size_t)(v * 3 + ci) * 512 + h) * 32 + m] = make_uint2(lo, hi);
        }
    }
}

// ---------------------------------------------------------------------------
// k_scat: gather T3 -> GB2. Thread owns one (v, n, h): reads 9 guarded uint2
// (ci x dy, h_src = h+dy-1), assembles 32 k-halves in registers, writes one
// contiguous 64B. Writes every cell incl. zero pads. grid (32 n, 3 v) x 256.
// ---------------------------------------------------------------------------
__global__ __launch_bounds__(256) void k_scat(float* __restrict__ ws) {
    const int n = blockIdx.x, v = blockIdx.y;
    const uint2* t3 = (const uint2*)(ws + OFF_T3);
    uint4* gb = (uint4*)ws;                                  // OFF_GB = 0

#pragma unroll
    for (int it = 0; it < 2; it++) {
        const int h = threadIdx.x + it * 256;
        union { unsigned short ks[32]; uint4 q[4]; } o;
#pragma unroll
        for (int t = 0; t < 4; t++) o.q[t] = make_uint4(0u, 0u, 0u, 0u);
#pragma unroll
        for (int ci = 0; ci < 3; ci++)
#pragma unroll
            for (int dy = 0; dy < 3; dy++) {
                const int hs = h + dy - 1;
                uint2 t2 = make_uint2(0u, 0u);
                if ((unsigned)hs < 512u)
                    t2 = t3[((size_t)(v * 3 + ci) * 512 + hs) * 32 + n];
                const int k = ci * 9 + dy * 3;
                o.ks[k]     = (unsigned short)(t2.x & 0xffffu);        // a0
                o.ks[k + 1] = (unsigned short)(t2.x >> 16);            // a1
                o.ks[k + 2] = (unsigned short)(t2.y & 0xffffu);        // a2
            }
        const size_t base = ((size_t)(v * 32 + n) * 512 + h) * 4;      // uint4 units
#pragma unroll
        for (int t = 0; t < 4; t++) gb[base + t] = o.q[t];
    }
}

// ---------------------------------------------------------------------------
// k_mlp: barrier-free (R20). Block 256 = 4 INDEPENDENT waves; wave w owns
// (32c tile, n = n0+w, all 512 h). Per 32-h chunk: stage-1 C[c][h] =
// cwB x GB2 (2x mfma f16) -> sigmoid -> bf16 into wave-private 2KB LDS
// tile (rows=c, swizzled) -> lgkmcnt -> A-frags -> stage-2 (2x mfma bf16).
// grid (24 ctile, 8 nquad, 3 v) = 576 blocks.
// ---------------------------------------------------------------------------
__global__ __launch_bounds__(256) void k_mlp(const float* __restrict__ cbp,
                                             MlpPtrs mp, float* __restrict__ ws) {
    const int v = blockIdx.z;
    const int c0 = blockIdx.x * 32;
    const int n0 = blockIdx.y * 4;
    const int tid = threadIdx.x;
    const int w = tid >> 6, lane = tid & 63;
    const int m = lane & 31, half = lane >> 5;

    __shared__ __align__(16) unsigned short y1t[4][1024];   // 2 KB per wave
    char* tb = (char*)&y1t[w][0];

    const unsigned short* cwB = (const unsigned short*)(ws + OFF_CWB);
    const f16x8 afA0 = *(const f16x8*)(cwB + (c0 + m) * 32 + half * 8);
    const f16x8 afA1 = *(const f16x8*)(cwB + (c0 + m) * 32 + 16 + half * 8);

    const uint4* w2pk = (const uint4*)(ws + OFF_SC) + (size_t)v * 2048 + lane;

    int rowv[16];
#pragma unroll
    for (int r = 0; r < 16; r++) rowv[r] = (r & 3) + 8 * (r >> 2) + 4 * half;

    const int nl = n0 + w;                           // this wave's n
    const float b1n = mp.b1[v][nl];
    const float s1n = ws[OFF_S1 + v * 32 + nl];
    float bases[16];
#pragma unroll
    for (int r = 0; r < 16; r++)
        bases[r] = b1n + cbp[c0 + rowv[r]] * s1n;

    const unsigned short* gbv = (const unsigned short*)ws
        + ((size_t)(v * 32 + nl) * 512) * 32;

    f32x16 acc;
#pragma unroll
    for (int r = 0; r < 16; r++) acc[r] = 0.f;

    const int byteA0 = (m * 64 + half * 16) ^ ((m & 7) << 4);
    const int byteA1 = (m * 64 + 32 + half * 16) ^ ((m & 7) << 4);

    f16x8 cb0 = *(const f16x8*)(gbv + (size_t)m * 32 + half * 8);
    f16x8 cb1 = *(const f16x8*)(gbv + (size_t)m * 32 + 16 + half * 8);
    uint4 cw0 = w2pk[0], cw1 = w2pk[64];

    for (int t = 0; t < 16; t++) {
        f16x8 nb0, nb1; uint4 nw0, nw1;
        if (t < 15) {                                // prefetch chunk t+1
            const size_t nbo = (size_t)((t + 1) * 32 + m) * 32;
            nb0 = *(const f16x8*)(gbv + nbo + half * 8);
            nb1 = *(const f16x8*)(gbv + nbo + 16 + half * 8);
            nw0 = w2pk[(t + 1) * 128];
            nw1 = w2pk[(t + 1) * 128 + 64];
        }
        f32x16 s1a;
#pragma unroll
        for (int r = 0; r < 16; r++) s1a[r] = 0.f;
        s1a = __builtin_amdgcn_mfma_f32_32x32x16_f16(afA0, cb0, s1a, 0, 0, 0);
        s1a = __builtin_amdgcn_mfma_f32_32x32x16_f16(afA1, cb1, s1a, 0, 0, 0);
#pragma unroll
        for (int r = 0; r < 16; r++) {
            float y = sigm(s1a[r] + bases[r]);
            const int row = rowv[r];                 // c-row
            const int byte = (row * 64 + m * 2) ^ ((row & 7) << 4);
            *(unsigned short*)(tb + byte) = f2bf(y);
        }
        asm volatile("s_waitcnt lgkmcnt(0)" ::: "memory");
        __builtin_amdgcn_sched_barrier(0);
        {
            bf16x8 a0 = *(const bf16x8*)(tb + byteA0);
            bf16x8 a1 = *(const bf16x8*)(tb + byteA1);
            union { uint4 u; bf16x8 b; } u0, u1;
            u0.u = cw0; u1.u = cw1;
            acc = __builtin_amdgcn_mfma_f32_32x32x16_bf16(a0, u0.b, acc, 0, 0, 0);
            acc = __builtin_amdgcn_mfma_f32_32x32x16_bf16(a1, u1.b, acc, 0, 0, 0);
        }
        if (t < 15) { cb0 = nb0; cb1 = nb1; cw0 = nw0; cw1 = nw1; }
    }

    const float b2v = mp.b2[v][m];
    unsigned short* uq = (unsigned short*)(ws + OFF_QKV);
#pragma unroll
    for (int r = 0; r < 16; r++) {
        const int c  = c0 + rowv[r];
        const int ny = nl;
        float mm = sigm(acc[r] + b2v);
        int head = ((m & 1) << 1) | (ny & 1);
        int sidx = ((m >> 1) << 4) | (ny >> 1);
        if (v < 2)  uq[v * 786432 + head * 196608 + c * 256 + sidx] = f2bf(mm);
        else        uq[2 * 786432 + head * 196608 + sidx * 768 + c] = f2bf(mm);
    }
}

// ---------------------------------------------------------------------------
// k_attn: fused QK^T * temp -> softmax -> @V for one (head, 32-row band).
// Block 512 = 8 waves. grid (24 iband, 4 head). (unchanged)
// ---------------------------------------------------------------------------
__global__ __launch_bounds__(512) void k_attn(const float* __restrict__ tempr,
                                              float* __restrict__ ws) {
    const unsigned short* uq = (const unsigned short*)(ws + OFF_QKV);
    const int head = blockIdx.y;
    const int i0 = blockIdx.x * 32;
    const int w = threadIdx.x >> 6, lane = threadIdx.x & 63;
    const int m = lane & 31, half = lane >> 5;

    __shared__ __align__(16) unsigned short ap[32][776];   // attn bf16, padded
    __shared__ float mxw[8][32];
    __shared__ float smw[8][32];
    __shared__ float gmx[32];
    __shared__ float gsm[32];

    const float temp = tempr[head];
    const unsigned short* Qp = uq + head * 196608 + (i0 + m) * 256 + half * 8;

    // ---- phase 1: QK^T for 3 j-tiles --------------------------------------
    f32x16 acc[3];
#pragma unroll
    for (int t = 0; t < 3; t++)
#pragma unroll
        for (int r = 0; r < 16; r++) acc[t][r] = 0.f;
#pragma unroll
    for (int t = 0; t < 3; t++) {
        const int j0 = (w * 3 + t) * 32;
        const unsigned short* Kp = uq + 786432 + head * 196608 + (j0 + m) * 256 + half * 8;
#pragma unroll
        for (int kk = 0; kk < 16; kk++) {
            bf16x8 af = *(const bf16x8*)(Qp + kk * 16);
            bf16x8 bf = *(const bf16x8*)(Kp + kk * 16);
            acc[t] = __builtin_amdgcn_mfma_f32_32x32x16_bf16(af, bf, acc[t], 0, 0, 0);
        }
    }
#pragma unroll
    for (int t = 0; t < 3; t++)
#pragma unroll
        for (int r = 0; r < 16; r++) acc[t][r] *= temp;

    // ---- phase 2: block softmax -------------------------------------------
    int rowv[16];
#pragma unroll
    for (int r = 0; r < 16; r++) rowv[r] = (r & 3) + 8 * (r >> 2) + 4 * half;

    float rmx[16];
#pragma unroll
    for (int r = 0; r < 16; r++)
        rmx[r] = fmaxf(fmaxf(acc[0][r], acc[1][r]), acc[2][r]);
#pragma unroll
    for (int off = 16; off > 0; off >>= 1)
#pragma unroll
        for (int r = 0; r < 16; r++) rmx[r] = fmaxf(rmx[r], __shfl_xor(rmx[r], off));
    if (m == 0) {
#pragma unroll
        for (int r = 0; r < 16; r++) mxw[w][rowv[r]] = rmx[r];
    }
    __syncthreads();
    if (threadIdx.x < 32) {
        float g = mxw[0][threadIdx.x];
#pragma unroll
        for (int ww = 1; ww < 8; ww++) g = fmaxf(g, mxw[ww][threadIdx.x]);
        gmx[threadIdx.x] = g;
    }
    __syncthreads();

    float rsm[16];
#pragma unroll
    for (int r = 0; r < 16; r++) {
        float gm = gmx[rowv[r]];
        float e0 = __expf(acc[0][r] - gm);
        float e1 = __expf(acc[1][r] - gm);
        float e2 = __expf(acc[2][r] - gm);
        acc[0][r] = e0; acc[1][r] = e1; acc[2][r] = e2;
        rsm[r] = (e0 + e1) + e2;
    }
#pragma unroll
    for (int off = 16; off > 0; off >>= 1)
#pragma unroll
        for (int r = 0; r < 16; r++) rsm[r] += __shfl_xor(rsm[r], off);
    if (m == 0) {
#pragma unroll
        for (int r = 0; r < 16; r++) smw[w][rowv[r]] = rsm[r];
    }
    __syncthreads();
    if (threadIdx.x < 32) {
        float g = smw[0][threadIdx.x];
#pragma unroll
        for (int ww = 1; ww < 8; ww++) g += smw[ww][threadIdx.x];
        gsm[threadIdx.x] = g;
    }
    __syncthreads();

    // ---- phase 3: attn bf16 -> LDS, then PV --------------------------------
#pragma unroll
    for (int r = 0; r < 16; r++) {
        float inv = __builtin_amdgcn_rcpf(gsm[rowv[r]]);
#pragma unroll
        for (int t = 0; t < 3; t++)
            ap[rowv[r]][(w * 3 + t) * 32 + m] = f2bf(acc[t][r] * inv);
    }
    __syncthreads();

    const int s0 = w * 32;
    const unsigned short* Vp = uq + 2 * 786432 + head * 196608 + (s0 + m) * 768 + half * 8;
    f32x16 po;
#pragma unroll
    for (int r = 0; r < 16; r++) po[r] = 0.f;
#pragma unroll
    for (int kk = 0; kk < 48; kk++) {
        bf16x8 af = *(const bf16x8*)&ap[m][half * 8 + kk * 16];
        bf16x8 bf = *(const bf16x8*)(Vp + kk * 16);
        po = __builtin_amdgcn_mfma_f32_32x32x16_bf16(af, bf, po, 0, 0, 0);
    }
    float* O = ws + OFF_ATT + head * 196608;
#pragma unroll
    for (int r = 0; r < 16; r++) {
        O[(i0 + rowv[r]) * 256 + s0 + m] = po[r];
    }
}

// ---------------------------------------------------------------------------
// k_ffn: fused pointwise(3->12) + dwconv3x3 + gelu-gate + pointwise(6->3)
// + residual, f32 store. 32x16 pixel tiles (512 blocks), 34x18 halo in LDS.
// ---------------------------------------------------------------------------
struct FfnPtrs { const float* p[6]; };  // pi_w, pi_b, dw_w, dw_b, po_w, po_b

__global__ __launch_bounds__(256) void k_ffn(const float* __restrict__ ws,
                                             const float* __restrict__ x,
                                             FfnPtrs fp,
                                             float* __restrict__ out) {
    const int x0 = blockIdx.x * 32, y0 = blockIdx.y * 16;
    __shared__ float wsm[192];
    __shared__ float p[12][612];
    const int tid = threadIdx.x;
    if (tid < 36)       wsm[tid] = fp.p[0][tid];          // pi_w (12,3)
    else if (tid < 48)  wsm[tid] = fp.p[1][tid - 36];     // pi_b (12)
    else if (tid < 156) wsm[tid] = fp.p[2][tid - 48];     // dw_w (12,9)
    else if (tid < 168) wsm[tid] = fp.p[3][tid - 156];    // dw_b (12)
    else if (tid < 186) wsm[tid] = fp.p[4][tid - 168];    // po_w (3,6)
    else if (tid < 189) wsm[tid] = fp.p[5][tid - 186];    // po_b (3)
    __syncthreads();

    const float* A = ws + OFF_ATT;
    for (int i = tid; i < 612; i += 256) {
        int py = i / 34, px = i % 34;
        int gy = y0 + py - 1, gx = x0 + px - 1;
        bool in = ((unsigned)gy < 512u) && ((unsigned)gx < 512u);
        float a0 = 0.f, a1 = 0.f, a2 = 0.f;
        if (in) {
            int b = gy * 512 + gx;
            a0 = A[b]; a1 = A[262144 + b]; a2 = A[524288 + b];
        }
#pragma unroll
        for (int j = 0; j < 12; j++) {
            float t = in ? (wsm[36 + j] + wsm[j * 3] * a0 + wsm[j * 3 + 1] * a1
                            + wsm[j * 3 + 2] * a2)
                         : 0.f;
            p[j][i] = t;
        }
    }
    __syncthreads();

#pragma unroll
    for (int it = 0; it < 2; it++) {
        int pl = tid + it * 256;
        int ly = pl >> 5, lx = pl & 31;
        float z[12];
#pragma unroll
        for (int j = 0; j < 12; j++) {
            const float* dw = &wsm[48 + j * 9];
            const float* pr = &p[j][ly * 34 + lx];
            z[j] = wsm[156 + j]
                 + dw[0] * pr[0]  + dw[1] * pr[1]  + dw[2] * pr[2]
                 + dw[3] * pr[34] + dw[4] * pr[35] + dw[5] * pr[36]
                 + dw[6] * pr[68] + dw[7] * pr[69] + dw[8] * pr[70];
        }
        float g[6];
#pragma unroll
        for (int j = 0; j < 6; j++) {
            float xx = z[j];
            g[j] = 0.5f * xx * (1.f + erff(xx * 0.70710678118f)) * z[6 + j];
        }
        int b = (y0 + ly) * 512 + (x0 + lx);
#pragma unroll
        for (int co = 0; co < 3; co++) {
            float r = wsm[186 + co];
#pragma unroll
            for (int j = 0; j < 6; j++) r = fmaf(wsm[168 + co * 6 + j], g[j], r);
            r += x[co * 262144 + b];             // residual
            out[co * 262144 + b] = r;
        }
    }
}

// ---------------------------------------------------------------------------
extern "C" void kernel_launch(void* const* d_in, const int* in_sizes, int n_in,
                              void* d_out, int out_size, void* d_ws, size_t ws_size,
                              hipStream_t stream) {
    float* ws = (float*)d_ws;
    float* out = (float*)d_out;
    const float* x   = (const float*)d_in[0];
    const float* cw  = (const float*)d_in[1];
    const float* cb  = (const float*)d_in[2];
    const float* qw1 = (const float*)d_in[3];
    const float* kw1 = (const float*)d_in[7];
    const float* vw1 = (const float*)d_in[11];
    const float* temp= (const float*)d_in[15];

    MlpPtrs mp;
    mp.b1[0] = (const float*)d_in[4];  mp.w2[0] = (const float*)d_in[5];  mp.b2[0] = (const float*)d_in[6];
    mp.b1[1] = (const float*)d_in[8];  mp.w2[1] = (const float*)d_in[9];  mp.b2[1] = (const float*)d_in[10];
    mp.b1[2] = (const float*)d_in[12]; mp.w2[2] = (const float*)d_in[13]; mp.b2[2] = (const float*)d_in[14];

    FfnPtrs fp;
    for (int i = 0; i < 6; i++) fp.p[i] = (const float*)d_in[16 + i];

    k_prep<<<123, 256, 0, stream>>>(qw1, kw1, vw1, cw, mp, ws);
    k_corr<<<dim3(16, 3, 3), 256, 0, stream>>>(x, ws);
    k_scat<<<dim3(32, 3), 256, 0, stream>>>(ws);
    k_mlp <<<dim3(24, 8, 3), 256, 0, stream>>>(cb, mp, ws);
    k_attn<<<dim3(24, 4), 512, 0, stream>>>(temp, ws);
    k_ffn <<<dim3(16, 32), 256, 0, stream>>>(ws, x, fp, out);
}